// Round 6
// baseline (323.185 us; speedup 1.0000x reference)
//
#include <hip/hip_runtime.h>
#include <hip/hip_bf16.h>
#include <cstdint>

#define SDIM 8192
#define DIN  4096
#define DOUT 4096
#define KAUG 4224   // 4096 + 8*16 LoRA extension
#define NADP 8
#define RLORA 16
#define NT 66       // K-tiles of 64

typedef __attribute__((ext_vector_type(8))) short short8;
typedef __attribute__((ext_vector_type(4))) float f32x4;

// ---------- conversion: f32 [rows][4096] -> bf16 [rows][KAUG] (first 4096 cols) ----------
__global__ void cvt_f32_to_bf16_aug(const float* __restrict__ src,
                                    __hip_bfloat16* __restrict__ dst,
                                    long total_elems) {
    long tid = (long)blockIdx.x * blockDim.x + threadIdx.x;
    long e = tid * 8;
    if (e >= total_elems) return;
    int s = (int)(e >> 12);
    int k = (int)(e & 4095);
    const float4* p = (const float4*)(src + e);
    float4 v0 = p[0], v1 = p[1];
    union { __hip_bfloat16 h[8]; short8 v; } u;
    u.h[0] = __float2bfloat16(v0.x); u.h[1] = __float2bfloat16(v0.y);
    u.h[2] = __float2bfloat16(v0.z); u.h[3] = __float2bfloat16(v0.w);
    u.h[4] = __float2bfloat16(v1.x); u.h[5] = __float2bfloat16(v1.y);
    u.h[6] = __float2bfloat16(v1.z); u.h[7] = __float2bfloat16(v1.w);
    *(short8*)(dst + (size_t)s * KAUG + k) = u.v;
}

// ---------- B tail into waug + A_all f32->bf16 into abf ----------
__global__ void prep_small(const float* __restrict__ B0, const float* __restrict__ A,
                           __hip_bfloat16* __restrict__ waug, __hip_bfloat16* __restrict__ abf) {
    int t = blockIdx.x * 256 + threadIdx.x;
    if (blockIdx.x < 2048) {           // btail: DOUT*128 elems
        int n = t >> 7, c = t & 127;
        int l = c >> 4, r = c & 15;
        waug[(size_t)n * KAUG + 4096 + c] =
            __float2bfloat16(B0[((size_t)l * DOUT + n) * RLORA + r]);
    } else {                           // A cvt: 128*4096 elems, 8/thread
        long e = (long)(t - 2048 * 256) * 8;
        const float4* p = (const float4*)(A + e);
        float4 v0 = p[0], v1 = p[1];
        union { __hip_bfloat16 h[8]; short8 v; } u;
        u.h[0] = __float2bfloat16(v0.x); u.h[1] = __float2bfloat16(v0.y);
        u.h[2] = __float2bfloat16(v0.z); u.h[3] = __float2bfloat16(v0.w);
        u.h[4] = __float2bfloat16(v1.x); u.h[5] = __float2bfloat16(v1.y);
        u.h[6] = __float2bfloat16(v1.z); u.h[7] = __float2bfloat16(v1.w);
        *(short8*)(abf + e) = u.v;
    }
}

// ---------- XA_all split-K mini-GEMM: part[kc][8192][128] = Xa[:, kc*1024:+1024] @ Ab^T ----------
__global__ __launch_bounds__(256) void xa_gemm(const __hip_bfloat16* __restrict__ Xa,
                                               const __hip_bfloat16* __restrict__ Ab,
                                               float* __restrict__ part) {
    __shared__ __attribute__((aligned(16))) char sm[32768];
    char* Xs = sm;              // [128][64] bf16
    char* As = sm + 16384;      // [128][64] bf16
    const int tid = threadIdx.x, lane = tid & 63, wave = tid >> 6;
    const int mt = blockIdx.x >> 2, kc = blockIdx.x & 3;
    const int row0 = mt * 128, k0 = kc * 1024;
    const int sr = tid >> 3;                 // 0..31
    const int cp = (tid & 7) ^ (sr & 7);
    const __hip_bfloat16* gX = Xa + (size_t)(row0 + sr) * KAUG + k0 + cp * 8;
    const __hip_bfloat16* gA = Ab + (size_t)sr * DIN + k0 + cp * 8;
    const int lr = lane & 15, lk = lane >> 4;
    f32x4 acc[2][8] = {};
    for (int kt = 0; kt < 16; ++kt) {
        #pragma unroll
        for (int i = 0; i < 4; ++i) {
            __builtin_amdgcn_global_load_lds((const uint32_t*)(gX + (size_t)(32 * i) * KAUG + kt * 64),
                                             (uint32_t*)(Xs + i * 4096 + tid * 16), 16, 0, 0);
            __builtin_amdgcn_global_load_lds((const uint32_t*)(gA + (size_t)(32 * i) * DIN + kt * 64),
                                             (uint32_t*)(As + i * 4096 + tid * 16), 16, 0, 0);
        }
        __syncthreads();
        #pragma unroll
        for (int kk = 0; kk < 2; ++kk) {
            short8 av[2], bv[8];
            #pragma unroll
            for (int m = 0; m < 2; ++m) {
                int row = wave * 32 + m * 16 + lr;
                int cc = (kk * 4 + lk) ^ (row & 7);
                av[m] = *(const short8*)(Xs + row * 128 + cc * 16);
            }
            #pragma unroll
            for (int n = 0; n < 8; ++n) {
                int row = n * 16 + lr;
                int cc = (kk * 4 + lk) ^ (row & 7);
                bv[n] = *(const short8*)(As + row * 128 + cc * 16);
            }
            #pragma unroll
            for (int m = 0; m < 2; ++m)
                #pragma unroll
                for (int n = 0; n < 8; ++n)
                    acc[m][n] = __builtin_amdgcn_mfma_f32_16x16x32_bf16(av[m], bv[n], acc[m][n], 0, 0, 0);
        }
        __syncthreads();
    }
    #pragma unroll
    for (int n = 0; n < 8; ++n) {
        int col = n * 16 + lr;
        #pragma unroll
        for (int m = 0; m < 2; ++m) {
            int r0 = wave * 32 + m * 16 + lk * 4;
            #pragma unroll
            for (int j = 0; j < 4; ++j)
                part[((size_t)kc << 20) + (size_t)(row0 + r0 + j) * 128 + col] = acc[m][n][j];
        }
    }
}

// ---------- reduce split-K partials, mask by adapter, scale, cvt -> xaug tail ----------
__global__ void xa_reduce(const float* __restrict__ part, const int* __restrict__ widx,
                          __hip_bfloat16* __restrict__ xaug) {
    int t = blockIdx.x * 256 + threadIdx.x;   // < 8192*128
    int s = t >> 7, c = t & 127;
    float sum = part[t] + part[(1 << 20) + t] + part[(2 << 20) + t] + part[(3 << 20) + t];
    int l = widx[s];
    float v = ((c >> 4) == l) ? 2.0f * sum : 0.0f;
    xaug[(size_t)s * KAUG + 4096 + c] = __float2bfloat16(v);
}

// ---------- 256x256 8-phase GEMM: out = Xaug @ Waug^T + bias ----------
// 8 waves (2M x 4N), per-wave 128x64, BK=64, LDS 128KB double-buffered.
// Phase = (M-half, kk): 16 mutually-independent MFMAs per phase, reads {8,8,8,0}.
// NO explicit lgkmcnt(0): compiler emits counted waits -> reads overlap MFMA.
// Counted vmcnt(4) at P4/P8 (ledger audited below).
__global__ __launch_bounds__(512, 2) void gemm8(const __hip_bfloat16* __restrict__ Xa,
                                                const __hip_bfloat16* __restrict__ Wa,
                                                const float* __restrict__ bias,
                                                float* __restrict__ out) {
    // layout: buf0.A [0,32K) buf0.B [32K,64K) buf1.A [64K,96K) buf1.B [96K,128K)
    __shared__ __attribute__((aligned(16))) char lds[131072];

    const int tid = threadIdx.x;
    const int lane = tid & 63, wave = tid >> 6;
    const int wm = wave >> 2, wn = wave & 3;
    const int lr = lane & 15, lk = lane >> 4;

    // bijective XCD swizzle (512 blocks, 512 % 8 == 0)
    int wg = blockIdx.x;
    int swz = (wg & 7) * 64 + (wg >> 3);
    int bm = swz >> 4, bn = swz & 15;
    const int rowA0 = bm * 256, colB0 = bn * 256;

    // staging: linear LDS dest, inverse-swizzled global source (rule #21).
    // LDS[r][c16] = G[r][c16 ^ (r&7)]
    const int sr = tid >> 3;
    const int cp = (tid & 7) ^ (sr & 7);
    const __hip_bfloat16* srcA = Xa + (size_t)(rowA0 + sr) * KAUG + cp * 8;
    const __hip_bfloat16* srcB = Wa + (size_t)(colB0 + sr) * KAUG + cp * 8;

    auto STAGE = [&](int buf, int mat, int half, int kt) {
        const __hip_bfloat16* s0 = (mat ? srcB : srcA) + (size_t)(half * 128) * KAUG + kt * 64;
        char* d = lds + buf * 65536 + mat * 32768 + half * 16384 + tid * 16;
        __builtin_amdgcn_global_load_lds((const uint32_t*)s0, (uint32_t*)d, 16, 0, 0);
        __builtin_amdgcn_global_load_lds((const uint32_t*)(s0 + (size_t)64 * KAUG),
                                         (uint32_t*)(d + 8192), 16, 0, 0);
    };

    f32x4 acc[8][4] = {};
    short8 aK0[4], aK1[4], bK0[4], bK1[4];   // per-kk fragment sets

    // 4 A-frags for (M-half mh, kk): rows wm*128 + mh*64 + m*16 + lr
    auto LDA_K = [&](short8 (&af)[4], int buf, int mh, int kk) {
        const char* base = lds + buf * 65536;
        #pragma unroll
        for (int m = 0; m < 4; ++m) {
            int row = wm * 128 + mh * 64 + m * 16 + lr;
            int cc = (kk * 4 + lk) ^ (row & 7);
            af[m] = *(const short8*)(base + row * 128 + cc * 16);
        }
    };
    // 4 B-frags (all N, one kk): rows wn*64 + n*16 + lr
    auto LDB_K = [&](short8 (&bf)[4], int buf, int kk) {
        const char* base = lds + buf * 65536 + 32768;
        #pragma unroll
        for (int n = 0; n < 4; ++n) {
            int row = wn * 64 + n * 16 + lr;
            int cc = (kk * 4 + lk) ^ (row & 7);
            bf[n] = *(const short8*)(base + row * 128 + cc * 16);
        }
    };

// 16 independent MFMAs (one kk, one M-half, all 4 N)
#define MMQ(AF, BF, MB)                                                            \
    do {                                                                           \
        __builtin_amdgcn_s_setprio(1);                                             \
        _Pragma("unroll")                                                          \
        for (int m = 0; m < 4; ++m)                                                \
            _Pragma("unroll")                                                      \
            for (int n = 0; n < 4; ++n)                                            \
                acc[(MB) + m][n] = __builtin_amdgcn_mfma_f32_16x16x32_bf16(        \
                    AF[m], BF[n], acc[(MB) + m][n], 0, 0, 0);                      \
        __builtin_amdgcn_s_setprio(0);                                             \
    } while (0)

#define BAR() __builtin_amdgcn_s_barrier()
#define VM4() asm volatile("s_waitcnt vmcnt(4)" ::: "memory")

    // prologue: buf0 <- t0 (8 loads); buf1.B <- t1 (4 loads)
    STAGE(0, 0, 0, 0); STAGE(0, 0, 1, 0);
    STAGE(0, 1, 0, 0); STAGE(0, 1, 1, 0);
    STAGE(1, 1, 0, 1); STAGE(1, 1, 1, 1);
    VM4();   // buf0 landed; 4 loads (buf1.B) in flight  == steady-state P1 entry
    BAR();

    #pragma unroll 1
    for (int i = 0; i < NT / 2; ++i) {
        int t1 = 2 * i + 1;
        int t2 = 2 * i + 2; if (t2 > NT - 1) t2 = NT - 1;   // clamp keeps vmcnt uniform
        int t3 = 2 * i + 3; if (t3 > NT - 1) t3 = NT - 1;
        // P1: (M0-3,kk0) on buf0; stage buf1.A.h0 <- t1 (buf1.A free since prev P7)
        LDA_K(aK0, 0, 0, 0); LDB_K(bK0, 0, 0);
        STAGE(1, 0, 0, t1);
        BAR();
        MMQ(aK0, bK0, 0);
        BAR();
        // P2: (M0-3,kk1); stage buf1.A.h1 <- t1
        LDA_K(aK1, 0, 0, 1); LDB_K(bK1, 0, 1);
        STAGE(1, 0, 1, t1);
        BAR();
        MMQ(aK1, bK1, 0);
        BAR();
        // P3: (M4-7,kk0); read both kk a47; stage buf0.B.h0 <- t2 (buf0.B reads done P2)
        LDA_K(aK0, 0, 1, 0); LDA_K(aK1, 0, 1, 1);
        STAGE(0, 1, 0, t2);
        BAR();
        MMQ(aK0, bK0, 4);
        BAR();
        // P4: (M4-7,kk1); no reads; stage buf0.B.h1 <- t2; vmcnt(4) -> buf1 (t1) fully landed
        STAGE(0, 1, 1, t2);
        VM4();
        BAR();
        MMQ(aK1, bK1, 4);
        BAR();
        // P5: buf1 (M0-3,kk0); stage buf0.A h0+h1 <- t2 (buf0.A reads done P3)
        LDA_K(aK0, 1, 0, 0); LDB_K(bK0, 1, 0);
        STAGE(0, 0, 0, t2); STAGE(0, 0, 1, t2);
        BAR();
        MMQ(aK0, bK0, 0);
        BAR();
        // P6: (M0-3,kk1); no stage
        LDA_K(aK1, 1, 0, 1); LDB_K(bK1, 1, 1);
        BAR();
        MMQ(aK1, bK1, 0);
        BAR();
        // P7: (M4-7,kk0); stage buf1.B.h0 <- t3 (buf1.B reads done P6)
        LDA_K(aK0, 1, 1, 0); LDA_K(aK1, 1, 1, 1);
        STAGE(1, 1, 0, t3);
        BAR();
        MMQ(aK0, bK0, 4);
        BAR();
        // P8: (M4-7,kk1); stage buf1.B.h1 <- t3; vmcnt(4) -> buf0 (t2) fully landed
        STAGE(1, 1, 1, t3);
        VM4();
        BAR();
        MMQ(aK1, bK1, 4);
        BAR();
    }

    // epilogue: C/D map col=lane&15, row=(lane>>4)*4+j  [m89]
    #pragma unroll
    for (int n = 0; n < 4; ++n) {
        int col = colB0 + wn * 64 + n * 16 + lr;
        float bv = bias[col];
        #pragma unroll
        for (int m = 0; m < 8; ++m) {
            int row0 = rowA0 + wm * 128 + m * 16 + lk * 4;
            #pragma unroll
            for (int j = 0; j < 4; ++j) {
                out[(size_t)(row0 + j) * DOUT + col] = acc[m][n][j] + bv;
            }
        }
    }
#undef MMQ
#undef BAR
#undef VM4
}

extern "C" void kernel_launch(void* const* d_in, const int* in_sizes, int n_in,
                              void* d_out, int out_size, void* d_ws, size_t ws_size,
                              hipStream_t stream) {
    const float* x      = (const float*)d_in[0];
    const float* weight = (const float*)d_in[1];
    const float* bias   = (const float*)d_in[2];
    const float* A_buf  = (const float*)d_in[3];
    const float* B_buf  = (const float*)d_in[4];
    const int*   widx   = (const int*)d_in[5];
    float* out = (float*)d_out;

    __hip_bfloat16* xaug = (__hip_bfloat16*)d_ws;                                    // [8192][4224]
    __hip_bfloat16* waug = (__hip_bfloat16*)((char*)d_ws + (size_t)SDIM * KAUG * 2); // [4096][4224]
    // d_out doubles as scratch before gemm8 overwrites it:
    __hip_bfloat16* abf  = (__hip_bfloat16*)d_out;                    // [128][4096] bf16 = 1MB
    float*          part = (float*)((char*)d_out + (1 << 20));        // [4][8192][128] f32 = 16MB

    // x -> bf16 into xaug[:, 0:4096]
    {
        long total = (long)SDIM * DIN;
        cvt_f32_to_bf16_aug<<<(int)((total / 8 + 255) / 256), 256, 0, stream>>>(x, xaug, total);
    }
    // weight -> bf16 into waug[:, 0:4096]
    {
        long total = (long)DOUT * DIN;
        cvt_f32_to_bf16_aug<<<(int)((total / 8 + 255) / 256), 256, 0, stream>>>(weight, waug, total);
    }
    // B tail into waug[:, 4096:] + A -> bf16
    prep_small<<<2048 + 256, 256, 0, stream>>>(B_buf, A_buf, waug, abf);
    // XA_all partials (split-K x4)
    xa_gemm<<<64 * 4, 256, 0, stream>>>(xaug, abf, part);
    // reduce + adapter mask + scale -> xaug tail
    xa_reduce<<<(SDIM * 128) / 256, 256, 0, stream>>>(part, widx, xaug);
    // 8-phase 256^2 GEMM + bias
    gemm8<<<(SDIM / 256) * (DOUT / 256), 512, 0, stream>>>(xaug, waug, bias, out);
}

// Round 7
// 320.226 us; speedup vs baseline: 1.0092x; 1.0092x over previous
//
#include <hip/hip_runtime.h>
#include <hip/hip_bf16.h>
#include <cstdint>

#define SDIM 8192
#define DIN  4096
#define DOUT 4096
#define KAUG 4224   // 4096 + 8*16 LoRA extension
#define NADP 8
#define RLORA 16
#define NT 66       // K-tiles of 64

typedef __attribute__((ext_vector_type(8))) short short8;
typedef __attribute__((ext_vector_type(4))) float f32x4;

// ---------- conversion: f32 [rows][4096] -> bf16 [rows][KAUG] (first 4096 cols) ----------
__global__ void cvt_f32_to_bf16_aug(const float* __restrict__ src,
                                    __hip_bfloat16* __restrict__ dst,
                                    long total_elems) {
    long tid = (long)blockIdx.x * blockDim.x + threadIdx.x;
    long e = tid * 8;
    if (e >= total_elems) return;
    int s = (int)(e >> 12);
    int k = (int)(e & 4095);
    const float4* p = (const float4*)(src + e);
    float4 v0 = p[0], v1 = p[1];
    union { __hip_bfloat16 h[8]; short8 v; } u;
    u.h[0] = __float2bfloat16(v0.x); u.h[1] = __float2bfloat16(v0.y);
    u.h[2] = __float2bfloat16(v0.z); u.h[3] = __float2bfloat16(v0.w);
    u.h[4] = __float2bfloat16(v1.x); u.h[5] = __float2bfloat16(v1.y);
    u.h[6] = __float2bfloat16(v1.z); u.h[7] = __float2bfloat16(v1.w);
    *(short8*)(dst + (size_t)s * KAUG + k) = u.v;
}

// ---------- B tail into waug + A_all f32->bf16 into abf ----------
__global__ void prep_small(const float* __restrict__ B0, const float* __restrict__ A,
                           __hip_bfloat16* __restrict__ waug, __hip_bfloat16* __restrict__ abf) {
    int t = blockIdx.x * 256 + threadIdx.x;
    if (blockIdx.x < 2048) {           // btail: DOUT*128 elems
        int n = t >> 7, c = t & 127;
        int l = c >> 4, r = c & 15;
        waug[(size_t)n * KAUG + 4096 + c] =
            __float2bfloat16(B0[((size_t)l * DOUT + n) * RLORA + r]);
    } else {                           // A cvt: 128*4096 elems, 8/thread
        long e = (long)(t - 2048 * 256) * 8;
        const float4* p = (const float4*)(A + e);
        float4 v0 = p[0], v1 = p[1];
        union { __hip_bfloat16 h[8]; short8 v; } u;
        u.h[0] = __float2bfloat16(v0.x); u.h[1] = __float2bfloat16(v0.y);
        u.h[2] = __float2bfloat16(v0.z); u.h[3] = __float2bfloat16(v0.w);
        u.h[4] = __float2bfloat16(v1.x); u.h[5] = __float2bfloat16(v1.y);
        u.h[6] = __float2bfloat16(v1.z); u.h[7] = __float2bfloat16(v1.w);
        *(short8*)(abf + e) = u.v;
    }
}

// ---------- XA_all split-K mini-GEMM: part[kc][8192][128] = Xa[:, kc*1024:+1024] @ Ab^T ----------
__global__ __launch_bounds__(256) void xa_gemm(const __hip_bfloat16* __restrict__ Xa,
                                               const __hip_bfloat16* __restrict__ Ab,
                                               float* __restrict__ part) {
    __shared__ __attribute__((aligned(16))) char sm[32768];
    char* Xs = sm;              // [128][64] bf16
    char* As = sm + 16384;      // [128][64] bf16
    const int tid = threadIdx.x, lane = tid & 63, wave = tid >> 6;
    const int mt = blockIdx.x >> 2, kc = blockIdx.x & 3;
    const int row0 = mt * 128, k0 = kc * 1024;
    const int sr = tid >> 3;                 // 0..31
    const int cp = (tid & 7) ^ (sr & 7);
    const __hip_bfloat16* gX = Xa + (size_t)(row0 + sr) * KAUG + k0 + cp * 8;
    const __hip_bfloat16* gA = Ab + (size_t)sr * DIN + k0 + cp * 8;
    const int lr = lane & 15, lk = lane >> 4;
    f32x4 acc[2][8] = {};
    for (int kt = 0; kt < 16; ++kt) {
        #pragma unroll
        for (int i = 0; i < 4; ++i) {
            __builtin_amdgcn_global_load_lds((const uint32_t*)(gX + (size_t)(32 * i) * KAUG + kt * 64),
                                             (uint32_t*)(Xs + i * 4096 + tid * 16), 16, 0, 0);
            __builtin_amdgcn_global_load_lds((const uint32_t*)(gA + (size_t)(32 * i) * DIN + kt * 64),
                                             (uint32_t*)(As + i * 4096 + tid * 16), 16, 0, 0);
        }
        __syncthreads();
        #pragma unroll
        for (int kk = 0; kk < 2; ++kk) {
            short8 av[2], bv[8];
            #pragma unroll
            for (int m = 0; m < 2; ++m) {
                int row = wave * 32 + m * 16 + lr;
                int cc = (kk * 4 + lk) ^ (row & 7);
                av[m] = *(const short8*)(Xs + row * 128 + cc * 16);
            }
            #pragma unroll
            for (int n = 0; n < 8; ++n) {
                int row = n * 16 + lr;
                int cc = (kk * 4 + lk) ^ (row & 7);
                bv[n] = *(const short8*)(As + row * 128 + cc * 16);
            }
            #pragma unroll
            for (int m = 0; m < 2; ++m)
                #pragma unroll
                for (int n = 0; n < 8; ++n)
                    acc[m][n] = __builtin_amdgcn_mfma_f32_16x16x32_bf16(av[m], bv[n], acc[m][n], 0, 0, 0);
        }
        __syncthreads();
    }
    #pragma unroll
    for (int n = 0; n < 8; ++n) {
        int col = n * 16 + lr;
        #pragma unroll
        for (int m = 0; m < 2; ++m) {
            int r0 = wave * 32 + m * 16 + lk * 4;
            #pragma unroll
            for (int j = 0; j < 4; ++j)
                part[((size_t)kc << 20) + (size_t)(row0 + r0 + j) * 128 + col] = acc[m][n][j];
        }
    }
}

// ---------- reduce split-K partials, mask by adapter, scale, cvt -> xaug tail ----------
__global__ void xa_reduce(const float* __restrict__ part, const int* __restrict__ widx,
                          __hip_bfloat16* __restrict__ xaug) {
    int t = blockIdx.x * 256 + threadIdx.x;   // < 8192*128
    int s = t >> 7, c = t & 127;
    float sum = part[t] + part[(1 << 20) + t] + part[(2 << 20) + t] + part[(3 << 20) + t];
    int l = widx[s];
    float v = ((c >> 4) == l) ? 2.0f * sum : 0.0f;
    xaug[(size_t)s * KAUG + 4096 + c] = __float2bfloat16(v);
}

// ---------- 256x256 8-phase GEMM, register-pipelined: out = Xaug @ Waug^T + bias ----------
// 8 waves (2M x 4N), per-wave 128x64, BK=64, LDS 128KB double-buffered.
// Phase p: {STAGE | [vmcnt(4)] | BAR | READS(p+1) | 16xMFMA(p) | BAR}.
// ds_reads for phase p+1 overlap MFMA issue of phase p (the 621-cyc matrix-pipe
// drain); MMQ operands were read one phase earlier -> counted lgkm wait only.
// Ledger audited: every STAGE(R) lands >=1 trailing-barrier after R's last read
// is consumed; vmcnt(4)@P4 drains buf1 (prologue-remnant+P1+P2), @P8 drains buf0
// (P3+P4+P5); 4 loads in flight is the loop invariant.
__global__ __launch_bounds__(512, 2) void gemm8(const __hip_bfloat16* __restrict__ Xa,
                                                const __hip_bfloat16* __restrict__ Wa,
                                                const float* __restrict__ bias,
                                                float* __restrict__ out) {
    // layout: buf0.A [0,32K) buf0.B [32K,64K) buf1.A [64K,96K) buf1.B [96K,128K)
    __shared__ __attribute__((aligned(16))) char lds[131072];

    const int tid = threadIdx.x;
    const int lane = tid & 63, wave = tid >> 6;
    const int wm = wave >> 2, wn = wave & 3;
    const int lr = lane & 15, lk = lane >> 4;

    // bijective XCD swizzle (512 blocks, 512 % 8 == 0)
    int wg = blockIdx.x;
    int swz = (wg & 7) * 64 + (wg >> 3);
    int bm = swz >> 4, bn = swz & 15;
    const int rowA0 = bm * 256, colB0 = bn * 256;

    // staging: linear LDS dest, inverse-swizzled global source (rule #21).
    // LDS[r][c16] = G[r][c16 ^ (r&7)]
    const int sr = tid >> 3;
    const int cp = (tid & 7) ^ (sr & 7);
    const __hip_bfloat16* srcA = Xa + (size_t)(rowA0 + sr) * KAUG + cp * 8;
    const __hip_bfloat16* srcB = Wa + (size_t)(colB0 + sr) * KAUG + cp * 8;

    auto STAGE = [&](int buf, int mat, int half, int kt) {
        const __hip_bfloat16* s0 = (mat ? srcB : srcA) + (size_t)(half * 128) * KAUG + kt * 64;
        char* d = lds + buf * 65536 + mat * 32768 + half * 16384 + tid * 16;
        __builtin_amdgcn_global_load_lds((const uint32_t*)s0, (uint32_t*)d, 16, 0, 0);
        __builtin_amdgcn_global_load_lds((const uint32_t*)(s0 + (size_t)64 * KAUG),
                                         (uint32_t*)(d + 8192), 16, 0, 0);
    };

    f32x4 acc[8][4] = {};
    short8 aA[4], aB[4], b0[4], b1[4];   // ping-pong fragment sets

    // 4 A-frags for (M-half mh, kk): rows wm*128 + mh*64 + m*16 + lr
    auto LDA_K = [&](short8 (&af)[4], int buf, int mh, int kk) {
        const char* base = lds + buf * 65536;
        #pragma unroll
        for (int m = 0; m < 4; ++m) {
            int row = wm * 128 + mh * 64 + m * 16 + lr;
            int cc = (kk * 4 + lk) ^ (row & 7);
            af[m] = *(const short8*)(base + row * 128 + cc * 16);
        }
    };
    // 4 B-frags (all N, one kk): rows wn*64 + n*16 + lr
    auto LDB_K = [&](short8 (&bf)[4], int buf, int kk) {
        const char* base = lds + buf * 65536 + 32768;
        #pragma unroll
        for (int n = 0; n < 4; ++n) {
            int row = wn * 64 + n * 16 + lr;
            int cc = (kk * 4 + lk) ^ (row & 7);
            bf[n] = *(const short8*)(base + row * 128 + cc * 16);
        }
    };

// 16 independent MFMAs (one kk, one M-half, all 4 N)
#define MMQ(AF, BF, MB)                                                            \
    do {                                                                           \
        __builtin_amdgcn_s_setprio(1);                                             \
        _Pragma("unroll")                                                          \
        for (int m = 0; m < 4; ++m)                                                \
            _Pragma("unroll")                                                      \
            for (int n = 0; n < 4; ++n)                                            \
                acc[(MB) + m][n] = __builtin_amdgcn_mfma_f32_16x16x32_bf16(        \
                    AF[m], BF[n], acc[(MB) + m][n], 0, 0, 0);                      \
        __builtin_amdgcn_s_setprio(0);                                             \
    } while (0)

#define BAR() __builtin_amdgcn_s_barrier()
#define VM4() asm volatile("s_waitcnt vmcnt(4)" ::: "memory")

    // prologue: buf0 <- t0 (8 loads); buf1.B <- t1 (4 loads)
    STAGE(0, 0, 0, 0); STAGE(0, 0, 1, 0);
    STAGE(0, 1, 0, 0); STAGE(0, 1, 1, 0);
    STAGE(1, 1, 0, 1); STAGE(1, 1, 1, 1);
    VM4();   // oldest 8 (buf0) landed; 4 (buf1.B) in flight == steady-state entry
    BAR();
    LDA_K(aA, 0, 0, 0); LDB_K(b0, 0, 0);   // READS(P1)

    #pragma unroll 1
    for (int i = 0; i < NT / 2; ++i) {
        int t1 = 2 * i + 1;
        int t2 = 2 * i + 2; if (t2 > NT - 1) t2 = NT - 1;   // clamp keeps vmcnt uniform
        int t3 = 2 * i + 3; if (t3 > NT - 1) t3 = NT - 1;
        // P1: MMQ buf0 (mh0,kk0); prefetch READS(P2); stage buf1.A.h0 <- t1
        STAGE(1, 0, 0, t1);
        BAR();
        LDA_K(aB, 0, 0, 1); LDB_K(b1, 0, 1);
        MMQ(aA, b0, 0);
        BAR();
        // P2: MMQ (mh0,kk1); READS(P3); stage buf1.A.h1 <- t1
        STAGE(1, 0, 1, t1);
        BAR();
        LDA_K(aA, 0, 1, 0);
        MMQ(aB, b1, 0);
        BAR();
        // P3: MMQ (mh1,kk0); READS(P4); stage buf0.B.h0 <- t2 (buf0.B reads consumed @P2)
        STAGE(0, 1, 0, t2);
        BAR();
        LDA_K(aB, 0, 1, 1);
        MMQ(aA, b0, 4);
        BAR();
        // P4: MMQ (mh1,kk1); stage buf0.B.h1 <- t2; vmcnt(4)+BAR -> buf1 (t1) landed;
        //     READS(P5) from buf1 (safe after the barrier)
        STAGE(0, 1, 1, t2);
        VM4();
        BAR();
        LDA_K(aA, 1, 0, 0); LDB_K(b0, 1, 0);
        MMQ(aB, b1, 4);
        BAR();
        // P5: MMQ buf1 (mh0,kk0); READS(P6); stage buf0.A h0+h1 <- t2 (buf0.A consumed @P4)
        STAGE(0, 0, 0, t2); STAGE(0, 0, 1, t2);
        BAR();
        LDA_K(aB, 1, 0, 1); LDB_K(b1, 1, 1);
        MMQ(aA, b0, 0);
        BAR();
        // P6: MMQ (mh0,kk1); READS(P7); no stage
        BAR();
        LDA_K(aA, 1, 1, 0);
        MMQ(aB, b1, 0);
        BAR();
        // P7: MMQ (mh1,kk0); READS(P8); stage buf1.B.h0 <- t3 (buf1.B reads consumed @P6)
        STAGE(1, 1, 0, t3);
        BAR();
        LDA_K(aB, 1, 1, 1);
        MMQ(aA, b0, 4);
        BAR();
        // P8: MMQ (mh1,kk1); stage buf1.B.h1 <- t3; vmcnt(4)+BAR -> buf0 (t2) landed;
        //     READS(P1-next) from buf0
        STAGE(1, 1, 1, t3);
        VM4();
        BAR();
        LDA_K(aA, 0, 0, 0); LDB_K(b0, 0, 0);
        MMQ(aB, b1, 4);
        BAR();
    }

    // epilogue: C/D map col=lane&15, row=(lane>>4)*4+j  [m89]
    #pragma unroll
    for (int n = 0; n < 4; ++n) {
        int col = colB0 + wn * 64 + n * 16 + lr;
        float bv = bias[col];
        #pragma unroll
        for (int m = 0; m < 8; ++m) {
            int row0 = rowA0 + wm * 128 + m * 16 + lk * 4;
            #pragma unroll
            for (int j = 0; j < 4; ++j) {
                out[(size_t)(row0 + j) * DOUT + col] = acc[m][n][j] + bv;
            }
        }
    }
#undef MMQ
#undef BAR
#undef VM4
}

extern "C" void kernel_launch(void* const* d_in, const int* in_sizes, int n_in,
                              void* d_out, int out_size, void* d_ws, size_t ws_size,
                              hipStream_t stream) {
    const float* x      = (const float*)d_in[0];
    const float* weight = (const float*)d_in[1];
    const float* bias   = (const float*)d_in[2];
    const float* A_buf  = (const float*)d_in[3];
    const float* B_buf  = (const float*)d_in[4];
    const int*   widx   = (const int*)d_in[5];
    float* out = (float*)d_out;

    __hip_bfloat16* xaug = (__hip_bfloat16*)d_ws;                                    // [8192][4224]
    __hip_bfloat16* waug = (__hip_bfloat16*)((char*)d_ws + (size_t)SDIM * KAUG * 2); // [4096][4224]
    // d_out doubles as scratch before gemm8 overwrites it:
    __hip_bfloat16* abf  = (__hip_bfloat16*)d_out;                    // [128][4096] bf16 = 1MB
    float*          part = (float*)((char*)d_out + (1 << 20));        // [4][8192][128] f32 = 16MB

    // x -> bf16 into xaug[:, 0:4096]
    {
        long total = (long)SDIM * DIN;
        cvt_f32_to_bf16_aug<<<(int)((total / 8 + 255) / 256), 256, 0, stream>>>(x, xaug, total);
    }
    // weight -> bf16 into waug[:, 0:4096]
    {
        long total = (long)DOUT * DIN;
        cvt_f32_to_bf16_aug<<<(int)((total / 8 + 255) / 256), 256, 0, stream>>>(weight, waug, total);
    }
    // B tail into waug[:, 4096:] + A -> bf16
    prep_small<<<2048 + 256, 256, 0, stream>>>(B_buf, A_buf, waug, abf);
    // XA_all partials (split-K x4)
    xa_gemm<<<64 * 4, 256, 0, stream>>>(xaug, abf, part);
    // reduce + adapter mask + scale -> xaug tail
    xa_reduce<<<(SDIM * 128) / 256, 256, 0, stream>>>(part, widx, xaug);
    // 8-phase 256^2 GEMM + bias
    gemm8<<<(SDIM / 256) * (DOUT / 256), 512, 0, stream>>>(xaug, waug, bias, out);
}

// Round 8
// 316.353 us; speedup vs baseline: 1.0216x; 1.0122x over previous
//
#include <hip/hip_runtime.h>
#include <hip/hip_bf16.h>
#include <cstdint>

#define SDIM 8192
#define DIN  4096
#define DOUT 4096
#define KAUG 4224   // 4096 + 8*16 LoRA extension
#define NADP 8
#define RLORA 16
#define NT 66       // K-tiles of 64

typedef __attribute__((ext_vector_type(8))) short short8;
typedef __attribute__((ext_vector_type(4))) float f32x4;

// ---------- fused prep: x->bf16, W->bf16, B-tail, A->bf16 in ONE launch ----------
// blocks [0, 16384): x cvt  (8 elems/thread)
// blocks [16384, 24576): W cvt
// blocks [24576, 26624): B tail
// blocks [26624, 26880): A cvt
__global__ __launch_bounds__(256) void prep_all(const float* __restrict__ x,
                         const float* __restrict__ W,
                         const float* __restrict__ B0,
                         const float* __restrict__ A,
                         __hip_bfloat16* __restrict__ xaug,
                         __hip_bfloat16* __restrict__ waug,
                         __hip_bfloat16* __restrict__ abf) {
    int b = blockIdx.x;
    if (b < 24576) {   // x or W conversion
        const float* src = (b < 16384) ? x : W;
        __hip_bfloat16* dst = (b < 16384) ? xaug : waug;
        long base = (b < 16384) ? (long)b * 2048 : (long)(b - 16384) * 2048;
        long e = base + (long)threadIdx.x * 8;
        int s = (int)(e >> 12);
        int k = (int)(e & 4095);
        const float4* p = (const float4*)(src + e);
        float4 v0 = p[0], v1 = p[1];
        union { __hip_bfloat16 h[8]; short8 v; } u;
        u.h[0] = __float2bfloat16(v0.x); u.h[1] = __float2bfloat16(v0.y);
        u.h[2] = __float2bfloat16(v0.z); u.h[3] = __float2bfloat16(v0.w);
        u.h[4] = __float2bfloat16(v1.x); u.h[5] = __float2bfloat16(v1.y);
        u.h[6] = __float2bfloat16(v1.z); u.h[7] = __float2bfloat16(v1.w);
        *(short8*)(dst + (size_t)s * KAUG + k) = u.v;
    } else if (b < 26624) {   // B tail: waug[n][4096 + l*16 + r] = B0[l][n][r]
        int t = (b - 24576) * 256 + threadIdx.x;
        int n = t >> 7, c = t & 127;
        int l = c >> 4, r = c & 15;
        waug[(size_t)n * KAUG + 4096 + c] =
            __float2bfloat16(B0[((size_t)l * DOUT + n) * RLORA + r]);
    } else {                  // A cvt: 128*4096 elems, 8/thread
        long e = ((long)(b - 26624) * 256 + threadIdx.x) * 8;
        const float4* p = (const float4*)(A + e);
        float4 v0 = p[0], v1 = p[1];
        union { __hip_bfloat16 h[8]; short8 v; } u;
        u.h[0] = __float2bfloat16(v0.x); u.h[1] = __float2bfloat16(v0.y);
        u.h[2] = __float2bfloat16(v0.z); u.h[3] = __float2bfloat16(v0.w);
        u.h[4] = __float2bfloat16(v1.x); u.h[5] = __float2bfloat16(v1.y);
        u.h[6] = __float2bfloat16(v1.z); u.h[7] = __float2bfloat16(v1.w);
        *(short8*)(abf + e) = u.v;
    }
}

// ---------- XA_all split-K mini-GEMM: part[kc][8192][128] = Xa[:, kc*1024:+1024] @ Ab^T ----------
__global__ __launch_bounds__(256) void xa_gemm(const __hip_bfloat16* __restrict__ Xa,
                                               const __hip_bfloat16* __restrict__ Ab,
                                               float* __restrict__ part) {
    __shared__ __attribute__((aligned(16))) char sm[32768];
    char* Xs = sm;              // [128][64] bf16
    char* As = sm + 16384;      // [128][64] bf16
    const int tid = threadIdx.x, lane = tid & 63, wave = tid >> 6;
    const int mt = blockIdx.x >> 2, kc = blockIdx.x & 3;
    const int row0 = mt * 128, k0 = kc * 1024;
    const int sr = tid >> 3;                 // 0..31
    const int cp = (tid & 7) ^ (sr & 7);
    const __hip_bfloat16* gX = Xa + (size_t)(row0 + sr) * KAUG + k0 + cp * 8;
    const __hip_bfloat16* gA = Ab + (size_t)sr * DIN + k0 + cp * 8;
    const int lr = lane & 15, lk = lane >> 4;
    f32x4 acc[2][8] = {};
    for (int kt = 0; kt < 16; ++kt) {
        #pragma unroll
        for (int i = 0; i < 4; ++i) {
            __builtin_amdgcn_global_load_lds((const uint32_t*)(gX + (size_t)(32 * i) * KAUG + kt * 64),
                                             (uint32_t*)(Xs + i * 4096 + tid * 16), 16, 0, 0);
            __builtin_amdgcn_global_load_lds((const uint32_t*)(gA + (size_t)(32 * i) * DIN + kt * 64),
                                             (uint32_t*)(As + i * 4096 + tid * 16), 16, 0, 0);
        }
        __syncthreads();
        #pragma unroll
        for (int kk = 0; kk < 2; ++kk) {
            short8 av[2], bv[8];
            #pragma unroll
            for (int m = 0; m < 2; ++m) {
                int row = wave * 32 + m * 16 + lr;
                int cc = (kk * 4 + lk) ^ (row & 7);
                av[m] = *(const short8*)(Xs + row * 128 + cc * 16);
            }
            #pragma unroll
            for (int n = 0; n < 8; ++n) {
                int row = n * 16 + lr;
                int cc = (kk * 4 + lk) ^ (row & 7);
                bv[n] = *(const short8*)(As + row * 128 + cc * 16);
            }
            #pragma unroll
            for (int m = 0; m < 2; ++m)
                #pragma unroll
                for (int n = 0; n < 8; ++n)
                    acc[m][n] = __builtin_amdgcn_mfma_f32_16x16x32_bf16(av[m], bv[n], acc[m][n], 0, 0, 0);
        }
        __syncthreads();
    }
    #pragma unroll
    for (int n = 0; n < 8; ++n) {
        int col = n * 16 + lr;
        #pragma unroll
        for (int m = 0; m < 2; ++m) {
            int r0 = wave * 32 + m * 16 + lk * 4;
            #pragma unroll
            for (int j = 0; j < 4; ++j)
                part[((size_t)kc << 20) + (size_t)(row0 + r0 + j) * 128 + col] = acc[m][n][j];
        }
    }
}

// ---------- reduce split-K partials, mask by adapter, scale, cvt -> xaug tail ----------
__global__ void xa_reduce(const float* __restrict__ part, const int* __restrict__ widx,
                          __hip_bfloat16* __restrict__ xaug) {
    int t = blockIdx.x * 256 + threadIdx.x;   // < 8192*128
    int s = t >> 7, c = t & 127;
    float sum = part[t] + part[(1 << 20) + t] + part[(2 << 20) + t] + part[(3 << 20) + t];
    int l = widx[s];
    float v = ((c >> 4) == l) ? 2.0f * sum : 0.0f;
    xaug[(size_t)s * KAUG + 4096 + c] = __float2bfloat16(v);
}

// ---------- 256x256 8-phase GEMM, register-pipelined + hoisted LDS addressing ----------
// 8 waves (2M x 4N), per-wave 128x64, BK=64, LDS 128KB double-buffered.
// All ds_read addresses = 1 of 8 precomputed VGPR bases + compile-time offset
// (row&7 == lane&7 for every fragment row, so the swizzled chunk is independent
// of m/mh/n). Zero per-phase VALU on the read path.
// Phase p: {STAGE | [vmcnt(4)] | BAR | READS(p+1) | 16xMFMA(p) | BAR}.
__global__ __launch_bounds__(512, 2) void gemm8(const __hip_bfloat16* __restrict__ Xa,
                                                const __hip_bfloat16* __restrict__ Wa,
                                                const float* __restrict__ bias,
                                                float* __restrict__ out) {
    // layout: buf0.A [0,32K) buf0.B [32K,64K) buf1.A [64K,96K) buf1.B [96K,128K)
    __shared__ __attribute__((aligned(16))) char lds[131072];

    const int tid = threadIdx.x;
    const int lane = tid & 63, wave = tid >> 6;
    const int wm = wave >> 2, wn = wave & 3;
    const int lr = lane & 15, lk = lane >> 4;

    // bijective XCD swizzle (512 blocks, 512 % 8 == 0)
    int wg = blockIdx.x;
    int swz = (wg & 7) * 64 + (wg >> 3);
    int bm = swz >> 4, bn = swz & 15;
    const int rowA0 = bm * 256, colB0 = bn * 256;

    // staging: linear LDS dest, inverse-swizzled global source (rule #21).
    // LDS[r][c16] = G[r][c16 ^ (r&7)]
    const int sr = tid >> 3;
    const int cp = (tid & 7) ^ (sr & 7);
    const __hip_bfloat16* srcA = Xa + (size_t)(rowA0 + sr) * KAUG + cp * 8;
    const __hip_bfloat16* srcB = Wa + (size_t)(colB0 + sr) * KAUG + cp * 8;
    char* const stgd = lds + tid * 16;   // hoisted stage dest base

    auto STAGE = [&](int buf, int mat, int half, int kt) {
        const __hip_bfloat16* s0 = (mat ? srcB : srcA) + (size_t)(half * 128) * KAUG + kt * 64;
        char* d = stgd + buf * 65536 + mat * 32768 + half * 16384;
        __builtin_amdgcn_global_load_lds((const uint32_t*)s0, (uint32_t*)d, 16, 0, 0);
        __builtin_amdgcn_global_load_lds((const uint32_t*)(s0 + (size_t)64 * KAUG),
                                         (uint32_t*)(d + 8192), 16, 0, 0);
    };

    // hoisted ds_read bases: [buf][kk] for A and B.
    // A byte addr = (wm*128 + mh*64 + m*16 + lr)*128 + ((kk*4+lk)^(lane&7))*16
    //            = adrA[buf][kk] + mh*8192 + m*2048        (offsets fit imm16)
    // B byte addr = 32768 + (wn*64 + n*16 + lr)*128 + cc*16
    //            = adrB[buf][kk] + n*2048
    const char* adrA[2][2];
    const char* adrB[2][2];
    #pragma unroll
    for (int kk = 0; kk < 2; ++kk) {
        int ccx = ((kk * 4 + lk) ^ (lane & 7)) * 16;
        adrA[0][kk] = lds + (wm * 128 + lr) * 128 + ccx;
        adrB[0][kk] = lds + 32768 + (wn * 64 + lr) * 128 + ccx;
        adrA[1][kk] = adrA[0][kk] + 65536;
        adrB[1][kk] = adrB[0][kk] + 65536;
    }

    f32x4 acc[8][4] = {};
    short8 aA[4], aB[4], b0[4], b1[4];   // ping-pong fragment sets

    // BUF/MH/KK/N are compile-time literals at every call site -> const-folded.
    auto LDA_K = [&](short8 (&af)[4], int buf, int mh, int kk) {
        const char* a0 = adrA[buf][kk] + mh * 8192;
        #pragma unroll
        for (int m = 0; m < 4; ++m)
            af[m] = *(const short8*)(a0 + m * 2048);
    };
    auto LDB_K = [&](short8 (&bf)[4], int buf, int kk) {
        const char* b0p = adrB[buf][kk];
        #pragma unroll
        for (int n = 0; n < 4; ++n)
            bf[n] = *(const short8*)(b0p + n * 2048);
    };

// 16 independent MFMAs (one kk, one M-half, all 4 N)
#define MMQ(AF, BF, MB)                                                            \
    do {                                                                           \
        __builtin_amdgcn_s_setprio(1);                                             \
        _Pragma("unroll")                                                          \
        for (int m = 0; m < 4; ++m)                                                \
            _Pragma("unroll")                                                      \
            for (int n = 0; n < 4; ++n)                                            \
                acc[(MB) + m][n] = __builtin_amdgcn_mfma_f32_16x16x32_bf16(        \
                    AF[m], BF[n], acc[(MB) + m][n], 0, 0, 0);                      \
        __builtin_amdgcn_s_setprio(0);                                             \
    } while (0)

#define BAR() __builtin_amdgcn_s_barrier()
#define VM4() asm volatile("s_waitcnt vmcnt(4)" ::: "memory")

    // prologue: buf0 <- t0 (8 loads); buf1.B <- t1 (4 loads)
    STAGE(0, 0, 0, 0); STAGE(0, 0, 1, 0);
    STAGE(0, 1, 0, 0); STAGE(0, 1, 1, 0);
    STAGE(1, 1, 0, 1); STAGE(1, 1, 1, 1);
    VM4();   // oldest 8 (buf0) landed; 4 (buf1.B) in flight == steady-state entry
    BAR();
    LDA_K(aA, 0, 0, 0); LDB_K(b0, 0, 0);   // READS(P1)

    #pragma unroll 1
    for (int i = 0; i < NT / 2; ++i) {
        int t1 = 2 * i + 1;
        int t2 = 2 * i + 2; if (t2 > NT - 1) t2 = NT - 1;   // clamp keeps vmcnt uniform
        int t3 = 2 * i + 3; if (t3 > NT - 1) t3 = NT - 1;
        // P1: MMQ buf0 (mh0,kk0); READS(P2); stage buf1.A.h0 <- t1
        STAGE(1, 0, 0, t1);
        BAR();
        LDA_K(aB, 0, 0, 1); LDB_K(b1, 0, 1);
        MMQ(aA, b0, 0);
        BAR();
        // P2: MMQ (mh0,kk1); READS(P3); stage buf1.A.h1 <- t1
        STAGE(1, 0, 1, t1);
        BAR();
        LDA_K(aA, 0, 1, 0);
        MMQ(aB, b1, 0);
        BAR();
        // P3: MMQ (mh1,kk0); READS(P4); stage buf0.B.h0 <- t2 (buf0.B reads consumed @P2)
        STAGE(0, 1, 0, t2);
        BAR();
        LDA_K(aB, 0, 1, 1);
        MMQ(aA, b0, 4);
        BAR();
        // P4: MMQ (mh1,kk1); stage buf0.B.h1 <- t2; vmcnt(4)+BAR -> buf1 (t1) landed;
        //     READS(P5) from buf1 (safe after the barrier)
        STAGE(0, 1, 1, t2);
        VM4();
        BAR();
        LDA_K(aA, 1, 0, 0); LDB_K(b0, 1, 0);
        MMQ(aB, b1, 4);
        BAR();
        // P5: MMQ buf1 (mh0,kk0); READS(P6); stage buf0.A h0+h1 <- t2 (buf0.A consumed @P4)
        STAGE(0, 0, 0, t2); STAGE(0, 0, 1, t2);
        BAR();
        LDA_K(aB, 1, 0, 1); LDB_K(b1, 1, 1);
        MMQ(aA, b0, 0);
        BAR();
        // P6: MMQ (mh0,kk1); READS(P7); no stage
        BAR();
        LDA_K(aA, 1, 1, 0);
        MMQ(aB, b1, 0);
        BAR();
        // P7: MMQ (mh1,kk0); READS(P8); stage buf1.B.h0 <- t3 (buf1.B reads consumed @P6)
        STAGE(1, 1, 0, t3);
        BAR();
        LDA_K(aB, 1, 1, 1);
        MMQ(aA, b0, 4);
        BAR();
        // P8: MMQ (mh1,kk1); stage buf1.B.h1 <- t3; vmcnt(4)+BAR -> buf0 (t2) landed;
        //     READS(P1-next) from buf0
        STAGE(1, 1, 1, t3);
        VM4();
        BAR();
        LDA_K(aA, 0, 0, 0); LDB_K(b0, 0, 0);
        MMQ(aB, b1, 4);
        BAR();
    }

    // epilogue: C/D map col=lane&15, row=(lane>>4)*4+j  [m89]
    #pragma unroll
    for (int n = 0; n < 4; ++n) {
        int col = colB0 + wn * 64 + n * 16 + lr;
        float bv = bias[col];
        #pragma unroll
        for (int m = 0; m < 8; ++m) {
            int row0 = rowA0 + wm * 128 + m * 16 + lk * 4;
            #pragma unroll
            for (int j = 0; j < 4; ++j) {
                out[(size_t)(row0 + j) * DOUT + col] = acc[m][n][j] + bv;
            }
        }
    }
#undef MMQ
#undef BAR
#undef VM4
}

extern "C" void kernel_launch(void* const* d_in, const int* in_sizes, int n_in,
                              void* d_out, int out_size, void* d_ws, size_t ws_size,
                              hipStream_t stream) {
    const float* x      = (const float*)d_in[0];
    const float* weight = (const float*)d_in[1];
    const float* bias   = (const float*)d_in[2];
    const float* A_buf  = (const float*)d_in[3];
    const float* B_buf  = (const float*)d_in[4];
    const int*   widx   = (const int*)d_in[5];
    float* out = (float*)d_out;

    __hip_bfloat16* xaug = (__hip_bfloat16*)d_ws;                                    // [8192][4224]
    __hip_bfloat16* waug = (__hip_bfloat16*)((char*)d_ws + (size_t)SDIM * KAUG * 2); // [4096][4224]
    // d_out doubles as scratch before gemm8 overwrites it:
    __hip_bfloat16* abf  = (__hip_bfloat16*)d_out;                    // [128][4096] bf16 = 1MB
    float*          part = (float*)((char*)d_out + (1 << 20));        // [4][8192][128] f32 = 16MB

    // fused prep: x->bf16, W->bf16, B-tail, A->bf16
    prep_all<<<26880, 256, 0, stream>>>(x, weight, B_buf, A_buf, xaug, waug, abf);
    // XA_all partials (split-K x4)
    xa_gemm<<<64 * 4, 256, 0, stream>>>(xaug, abf, part);
    // reduce + adapter mask + scale -> xaug tail
    xa_reduce<<<(SDIM * 128) / 256, 256, 0, stream>>>(part, widx, xaug);
    // 8-phase 256^2 GEMM + bias
    gemm8<<<(SDIM / 256) * (DOUT / 256), 512, 0, stream>>>(xaug, waug, bias, out);
}

// Round 9
// 316.034 us; speedup vs baseline: 1.0226x; 1.0010x over previous
//
#include <hip/hip_runtime.h>
#include <hip/hip_bf16.h>
#include <cstdint>

#define SDIM 8192
#define DIN  4096
#define DOUT 4096
#define KAUG 4224   // 4096 + 8*16 LoRA extension
#define NADP 8
#define RLORA 16
#define NT 66       // K-tiles of 64

typedef __attribute__((ext_vector_type(8))) short short8;
typedef __attribute__((ext_vector_type(4))) float f32x4;

// ---------- fused prep: x->bf16, W->bf16, B-tail, A->bf16 in ONE launch ----------
__global__ __launch_bounds__(256) void prep_all(const float* __restrict__ x,
                         const float* __restrict__ W,
                         const float* __restrict__ B0,
                         const float* __restrict__ A,
                         __hip_bfloat16* __restrict__ xaug,
                         __hip_bfloat16* __restrict__ waug,
                         __hip_bfloat16* __restrict__ abf) {
    int b = blockIdx.x;
    if (b < 24576) {   // x or W conversion
        const float* src = (b < 16384) ? x : W;
        __hip_bfloat16* dst = (b < 16384) ? xaug : waug;
        long base = (b < 16384) ? (long)b * 2048 : (long)(b - 16384) * 2048;
        long e = base + (long)threadIdx.x * 8;
        int s = (int)(e >> 12);
        int k = (int)(e & 4095);
        const float4* p = (const float4*)(src + e);
        float4 v0 = p[0], v1 = p[1];
        union { __hip_bfloat16 h[8]; short8 v; } u;
        u.h[0] = __float2bfloat16(v0.x); u.h[1] = __float2bfloat16(v0.y);
        u.h[2] = __float2bfloat16(v0.z); u.h[3] = __float2bfloat16(v0.w);
        u.h[4] = __float2bfloat16(v1.x); u.h[5] = __float2bfloat16(v1.y);
        u.h[6] = __float2bfloat16(v1.z); u.h[7] = __float2bfloat16(v1.w);
        *(short8*)(dst + (size_t)s * KAUG + k) = u.v;
    } else if (b < 26624) {   // B tail: waug[n][4096 + l*16 + r] = B0[l][n][r]
        int t = (b - 24576) * 256 + threadIdx.x;
        int n = t >> 7, c = t & 127;
        int l = c >> 4, r = c & 15;
        waug[(size_t)n * KAUG + 4096 + c] =
            __float2bfloat16(B0[((size_t)l * DOUT + n) * RLORA + r]);
    } else {                  // A cvt: 128*4096 elems, 8/thread
        long e = ((long)(b - 26624) * 256 + threadIdx.x) * 8;
        const float4* p = (const float4*)(A + e);
        float4 v0 = p[0], v1 = p[1];
        union { __hip_bfloat16 h[8]; short8 v; } u;
        u.h[0] = __float2bfloat16(v0.x); u.h[1] = __float2bfloat16(v0.y);
        u.h[2] = __float2bfloat16(v0.z); u.h[3] = __float2bfloat16(v0.w);
        u.h[4] = __float2bfloat16(v1.x); u.h[5] = __float2bfloat16(v1.y);
        u.h[6] = __float2bfloat16(v1.z); u.h[7] = __float2bfloat16(v1.w);
        *(short8*)(abf + e) = u.v;
    }
}

// ---------- XA_all split-K mini-GEMM: part[kc][8192][128] = Xa[:, kc*1024:+1024] @ Ab^T ----------
__global__ __launch_bounds__(256) void xa_gemm(const __hip_bfloat16* __restrict__ Xa,
                                               const __hip_bfloat16* __restrict__ Ab,
                                               float* __restrict__ part) {
    __shared__ __attribute__((aligned(16))) char sm[32768];
    char* Xs = sm;              // [128][64] bf16
    char* As = sm + 16384;      // [128][64] bf16
    const int tid = threadIdx.x, lane = tid & 63, wave = tid >> 6;
    const int mt = blockIdx.x >> 2, kc = blockIdx.x & 3;
    const int row0 = mt * 128, k0 = kc * 1024;
    const int sr = tid >> 3;                 // 0..31
    const int cp = (tid & 7) ^ (sr & 7);
    const __hip_bfloat16* gX = Xa + (size_t)(row0 + sr) * KAUG + k0 + cp * 8;
    const __hip_bfloat16* gA = Ab + (size_t)sr * DIN + k0 + cp * 8;
    const int lr = lane & 15, lk = lane >> 4;
    f32x4 acc[2][8] = {};
    for (int kt = 0; kt < 16; ++kt) {
        #pragma unroll
        for (int i = 0; i < 4; ++i) {
            __builtin_amdgcn_global_load_lds((const uint32_t*)(gX + (size_t)(32 * i) * KAUG + kt * 64),
                                             (uint32_t*)(Xs + i * 4096 + tid * 16), 16, 0, 0);
            __builtin_amdgcn_global_load_lds((const uint32_t*)(gA + (size_t)(32 * i) * DIN + kt * 64),
                                             (uint32_t*)(As + i * 4096 + tid * 16), 16, 0, 0);
        }
        __syncthreads();
        #pragma unroll
        for (int kk = 0; kk < 2; ++kk) {
            short8 av[2], bv[8];
            #pragma unroll
            for (int m = 0; m < 2; ++m) {
                int row = wave * 32 + m * 16 + lr;
                int cc = (kk * 4 + lk) ^ (row & 7);
                av[m] = *(const short8*)(Xs + row * 128 + cc * 16);
            }
            #pragma unroll
            for (int n = 0; n < 8; ++n) {
                int row = n * 16 + lr;
                int cc = (kk * 4 + lk) ^ (row & 7);
                bv[n] = *(const short8*)(As + row * 128 + cc * 16);
            }
            #pragma unroll
            for (int m = 0; m < 2; ++m)
                #pragma unroll
                for (int n = 0; n < 8; ++n)
                    acc[m][n] = __builtin_amdgcn_mfma_f32_16x16x32_bf16(av[m], bv[n], acc[m][n], 0, 0, 0);
        }
        __syncthreads();
    }
    #pragma unroll
    for (int n = 0; n < 8; ++n) {
        int col = n * 16 + lr;
        #pragma unroll
        for (int m = 0; m < 2; ++m) {
            int r0 = wave * 32 + m * 16 + lk * 4;
            #pragma unroll
            for (int j = 0; j < 4; ++j)
                part[((size_t)kc << 20) + (size_t)(row0 + r0 + j) * 128 + col] = acc[m][n][j];
        }
    }
}

// ---------- reduce split-K partials, mask by adapter, scale, cvt -> xaug tail ----------
__global__ void xa_reduce(const float* __restrict__ part, const int* __restrict__ widx,
                          __hip_bfloat16* __restrict__ xaug) {
    int t = blockIdx.x * 256 + threadIdx.x;   // < 8192*128
    int s = t >> 7, c = t & 127;
    float sum = part[t] + part[(1 << 20) + t] + part[(2 << 20) + t] + part[(3 << 20) + t];
    int l = widx[s];
    float v = ((c >> 4) == l) ? 2.0f * sum : 0.0f;
    xaug[(size_t)s * KAUG + 4096 + c] = __float2bfloat16(v);
}

// ---------- 256x256 8-phase GEMM, m201-exact phase ordering ----------
// 8 waves (2M x 4N), per-wave 128x64, BK=64, LDS 128KB double-buffered.
// Phase p: {STAGE | [vmcnt(4)] | in-phase ds_reads | BAR | lgkmcnt(0) +
//   sched_barrier(0) | setprio(1) 16xMFMA-uninterrupted setprio(0) | BAR}.
// The single drain-all + fence (rule #18) keeps the 16-MFMA cluster free of
// interleaved counted s_waitcnt; reads drain while other waves reach the BAR.
// vmcnt(4) ledger (audited, R6): P4 drains buf1 (P1+P2+prologue), P8 drains
// buf0 (P3+P4+P5); 4 loads in flight is the loop invariant.
__global__ __launch_bounds__(512, 2) void gemm8(const __hip_bfloat16* __restrict__ Xa,
                                                const __hip_bfloat16* __restrict__ Wa,
                                                const float* __restrict__ bias,
                                                float* __restrict__ out) {
    // layout: buf0.A [0,32K) buf0.B [32K,64K) buf1.A [64K,96K) buf1.B [96K,128K)
    __shared__ __attribute__((aligned(16))) char lds[131072];

    const int tid = threadIdx.x;
    const int lane = tid & 63, wave = tid >> 6;
    const int wm = wave >> 2, wn = wave & 3;
    const int lr = lane & 15, lk = lane >> 4;

    // bijective XCD swizzle (512 blocks, 512 % 8 == 0)
    int wg = blockIdx.x;
    int swz = (wg & 7) * 64 + (wg >> 3);
    int bm = swz >> 4, bn = swz & 15;
    const int rowA0 = bm * 256, colB0 = bn * 256;

    // staging: linear LDS dest, inverse-swizzled global source (rule #21).
    // LDS[r][c16] = G[r][c16 ^ (r&7)]
    const int sr = tid >> 3;
    const int cp = (tid & 7) ^ (sr & 7);
    const __hip_bfloat16* srcA = Xa + (size_t)(rowA0 + sr) * KAUG + cp * 8;
    const __hip_bfloat16* srcB = Wa + (size_t)(colB0 + sr) * KAUG + cp * 8;
    char* const stgd = lds + tid * 16;

    auto STAGE = [&](int buf, int mat, int half, int kt) {
        const __hip_bfloat16* s0 = (mat ? srcB : srcA) + (size_t)(half * 128) * KAUG + kt * 64;
        char* d = stgd + buf * 65536 + mat * 32768 + half * 16384;
        __builtin_amdgcn_global_load_lds((const uint32_t*)s0, (uint32_t*)d, 16, 0, 0);
        __builtin_amdgcn_global_load_lds((const uint32_t*)(s0 + (size_t)64 * KAUG),
                                         (uint32_t*)(d + 8192), 16, 0, 0);
    };

    // hoisted ds_read bases: row&7 == lane&7 for every fragment row, so the
    // swizzled chunk is independent of m/mh/n -> base + compile-time offset.
    const char* adrA[2][2];
    const char* adrB[2][2];
    #pragma unroll
    for (int kk = 0; kk < 2; ++kk) {
        int ccx = ((kk * 4 + lk) ^ (lane & 7)) * 16;
        adrA[0][kk] = lds + (wm * 128 + lr) * 128 + ccx;
        adrB[0][kk] = lds + 32768 + (wn * 64 + lr) * 128 + ccx;
        adrA[1][kk] = adrA[0][kk] + 65536;
        adrB[1][kk] = adrB[0][kk] + 65536;
    }

    f32x4 acc[8][4] = {};
    short8 a[4], b0[4], b1[4];

    auto LDA_K = [&](short8 (&af)[4], int buf, int mh, int kk) {
        const char* a0 = adrA[buf][kk] + mh * 8192;
        #pragma unroll
        for (int m = 0; m < 4; ++m)
            af[m] = *(const short8*)(a0 + m * 2048);
    };
    auto LDB_K = [&](short8 (&bf)[4], int buf, int kk) {
        const char* b0p = adrB[buf][kk];
        #pragma unroll
        for (int n = 0; n < 4; ++n)
            bf[n] = *(const short8*)(b0p + n * 2048);
    };

// drain-all + fence, then 16 uninterrupted MFMAs
#define MMQ(AF, BF, MB)                                                            \
    do {                                                                           \
        asm volatile("s_waitcnt lgkmcnt(0)" ::: "memory");                         \
        __builtin_amdgcn_sched_barrier(0);                                         \
        __builtin_amdgcn_s_setprio(1);                                             \
        _Pragma("unroll")                                                          \
        for (int m = 0; m < 4; ++m)                                                \
            _Pragma("unroll")                                                      \
            for (int n = 0; n < 4; ++n)                                            \
                acc[(MB) + m][n] = __builtin_amdgcn_mfma_f32_16x16x32_bf16(        \
                    AF[m], BF[n], acc[(MB) + m][n], 0, 0, 0);                      \
        __builtin_amdgcn_s_setprio(0);                                             \
    } while (0)

#define BAR() __builtin_amdgcn_s_barrier()
#define VM4() asm volatile("s_waitcnt vmcnt(4)" ::: "memory")

    // prologue: buf0 <- t0 (8 loads); buf1.B <- t1 (4 loads)
    STAGE(0, 0, 0, 0); STAGE(0, 0, 1, 0);
    STAGE(0, 1, 0, 0); STAGE(0, 1, 1, 0);
    STAGE(1, 1, 0, 1); STAGE(1, 1, 1, 1);
    VM4();   // buf0 landed; 4 (buf1.B) in flight == steady-state entry
    BAR();

    #pragma unroll 1
    for (int i = 0; i < NT / 2; ++i) {
        int t1 = 2 * i + 1;
        int t2 = 2 * i + 2; if (t2 > NT - 1) t2 = NT - 1;   // clamp keeps vmcnt uniform
        int t3 = 2 * i + 3; if (t3 > NT - 1) t3 = NT - 1;
        // P1: (mh0,kk0) on buf0; stage buf1.A.h0 <- t1
        STAGE(1, 0, 0, t1);
        LDA_K(a, 0, 0, 0); LDB_K(b0, 0, 0);
        BAR();
        MMQ(a, b0, 0);
        BAR();
        // P2: (mh0,kk1); stage buf1.A.h1 <- t1
        STAGE(1, 0, 1, t1);
        LDA_K(a, 0, 0, 1); LDB_K(b1, 0, 1);
        BAR();
        MMQ(a, b1, 0);
        BAR();
        // P3: (mh1,kk0); stage buf0.B.h0 <- t2 (buf0.B reads done by end P2)
        STAGE(0, 1, 0, t2);
        LDA_K(a, 0, 1, 0);
        BAR();
        MMQ(a, b0, 4);
        BAR();
        // P4: (mh1,kk1); stage buf0.B.h1 <- t2; vmcnt(4) -> buf1 (t1) fully landed
        STAGE(0, 1, 1, t2);
        VM4();
        LDA_K(a, 0, 1, 1);
        BAR();
        MMQ(a, b1, 4);
        BAR();
        // P5: buf1 (mh0,kk0); stage buf0.A h0+h1 <- t2 (buf0.A reads done by end P4)
        STAGE(0, 0, 0, t2); STAGE(0, 0, 1, t2);
        LDA_K(a, 1, 0, 0); LDB_K(b0, 1, 0);
        BAR();
        MMQ(a, b0, 0);
        BAR();
        // P6: (mh0,kk1); no stage
        LDA_K(a, 1, 0, 1); LDB_K(b1, 1, 1);
        BAR();
        MMQ(a, b1, 0);
        BAR();
        // P7: (mh1,kk0); stage buf1.B.h0 <- t3 (buf1.B reads done by end P6)
        STAGE(1, 1, 0, t3);
        LDA_K(a, 1, 1, 0);
        BAR();
        MMQ(a, b0, 4);
        BAR();
        // P8: (mh1,kk1); stage buf1.B.h1 <- t3; vmcnt(4) -> buf0 (t2) fully landed
        STAGE(1, 1, 1, t3);
        VM4();
        LDA_K(a, 1, 1, 1);
        BAR();
        MMQ(a, b1, 4);
        BAR();
    }

    // epilogue: C/D map col=lane&15, row=(lane>>4)*4+j  [m89]
    #pragma unroll
    for (int n = 0; n < 4; ++n) {
        int col = colB0 + wn * 64 + n * 16 + lr;
        float bv = bias[col];
        #pragma unroll
        for (int m = 0; m < 8; ++m) {
            int row0 = rowA0 + wm * 128 + m * 16 + lk * 4;
            #pragma unroll
            for (int j = 0; j < 4; ++j) {
                out[(size_t)(row0 + j) * DOUT + col] = acc[m][n][j] + bv;
            }
        }
    }
#undef MMQ
#undef BAR
#undef VM4
}

extern "C" void kernel_launch(void* const* d_in, const int* in_sizes, int n_in,
                              void* d_out, int out_size, void* d_ws, size_t ws_size,
                              hipStream_t stream) {
    const float* x      = (const float*)d_in[0];
    const float* weight = (const float*)d_in[1];
    const float* bias   = (const float*)d_in[2];
    const float* A_buf  = (const float*)d_in[3];
    const float* B_buf  = (const float*)d_in[4];
    const int*   widx   = (const int*)d_in[5];
    float* out = (float*)d_out;

    __hip_bfloat16* xaug = (__hip_bfloat16*)d_ws;                                    // [8192][4224]
    __hip_bfloat16* waug = (__hip_bfloat16*)((char*)d_ws + (size_t)SDIM * KAUG * 2); // [4096][4224]
    // d_out doubles as scratch before gemm8 overwrites it:
    __hip_bfloat16* abf  = (__hip_bfloat16*)d_out;                    // [128][4096] bf16 = 1MB
    float*          part = (float*)((char*)d_out + (1 << 20));        // [4][8192][128] f32 = 16MB

    // fused prep: x->bf16, W->bf16, B-tail, A->bf16
    prep_all<<<26880, 256, 0, stream>>>(x, weight, B_buf, A_buf, xaug, waug, abf);
    // XA_all partials (split-K x4)
    xa_gemm<<<64 * 4, 256, 0, stream>>>(xaug, abf, part);
    // reduce + adapter mask + scale -> xaug tail
    xa_reduce<<<(SDIM * 128) / 256, 256, 0, stream>>>(part, widx, xaug);
    // 8-phase 256^2 GEMM + bias
    gemm8<<<(SDIM / 256) * (DOUT / 256), 512, 0, stream>>>(xaug, waug, bias, out);
}

// Round 10
// 312.903 us; speedup vs baseline: 1.0329x; 1.0100x over previous
//
#include <hip/hip_runtime.h>
#include <hip/hip_bf16.h>
#include <cstdint>

#define SDIM 8192
#define DIN  4096
#define DOUT 4096
#define KAUG 4224   // 4096 + 8*16 LoRA extension
#define NADP 8
#define RLORA 16
#define NT 66       // K-tiles of 64

typedef __attribute__((ext_vector_type(8))) short short8;
typedef __attribute__((ext_vector_type(4))) float f32x4;

// ---------- fused prep: x->bf16, W->bf16, B-tail, A->bf16 in ONE launch ----------
__global__ __launch_bounds__(256) void prep_all(const float* __restrict__ x,
                         const float* __restrict__ W,
                         const float* __restrict__ B0,
                         const float* __restrict__ A,
                         __hip_bfloat16* __restrict__ xaug,
                         __hip_bfloat16* __restrict__ waug,
                         __hip_bfloat16* __restrict__ abf) {
    int b = blockIdx.x;
    if (b < 24576) {   // x or W conversion
        const float* src = (b < 16384) ? x : W;
        __hip_bfloat16* dst = (b < 16384) ? xaug : waug;
        long base = (b < 16384) ? (long)b * 2048 : (long)(b - 16384) * 2048;
        long e = base + (long)threadIdx.x * 8;
        int s = (int)(e >> 12);
        int k = (int)(e & 4095);
        const float4* p = (const float4*)(src + e);
        float4 v0 = p[0], v1 = p[1];
        union { __hip_bfloat16 h[8]; short8 v; } u;
        u.h[0] = __float2bfloat16(v0.x); u.h[1] = __float2bfloat16(v0.y);
        u.h[2] = __float2bfloat16(v0.z); u.h[3] = __float2bfloat16(v0.w);
        u.h[4] = __float2bfloat16(v1.x); u.h[5] = __float2bfloat16(v1.y);
        u.h[6] = __float2bfloat16(v1.z); u.h[7] = __float2bfloat16(v1.w);
        *(short8*)(dst + (size_t)s * KAUG + k) = u.v;
    } else if (b < 26624) {   // B tail: waug[n][4096 + l*16 + r] = B0[l][n][r]
        int t = (b - 24576) * 256 + threadIdx.x;
        int n = t >> 7, c = t & 127;
        int l = c >> 4, r = c & 15;
        waug[(size_t)n * KAUG + 4096 + c] =
            __float2bfloat16(B0[((size_t)l * DOUT + n) * RLORA + r]);
    } else {                  // A cvt: 128*4096 elems, 8/thread
        long e = ((long)(b - 26624) * 256 + threadIdx.x) * 8;
        const float4* p = (const float4*)(A + e);
        float4 v0 = p[0], v1 = p[1];
        union { __hip_bfloat16 h[8]; short8 v; } u;
        u.h[0] = __float2bfloat16(v0.x); u.h[1] = __float2bfloat16(v0.y);
        u.h[2] = __float2bfloat16(v0.z); u.h[3] = __float2bfloat16(v0.w);
        u.h[4] = __float2bfloat16(v1.x); u.h[5] = __float2bfloat16(v1.y);
        u.h[6] = __float2bfloat16(v1.z); u.h[7] = __float2bfloat16(v1.w);
        *(short8*)(abf + e) = u.v;
    }
}

// ---------- XA_all split-K mini-GEMM: part[kc][8192][128] = Xa[:, kc*1024:+1024] @ Ab^T ----------
__global__ __launch_bounds__(256) void xa_gemm(const __hip_bfloat16* __restrict__ Xa,
                                               const __hip_bfloat16* __restrict__ Ab,
                                               float* __restrict__ part) {
    __shared__ __attribute__((aligned(16))) char sm[32768];
    char* Xs = sm;              // [128][64] bf16
    char* As = sm + 16384;      // [128][64] bf16
    const int tid = threadIdx.x, lane = tid & 63, wave = tid >> 6;
    const int mt = blockIdx.x >> 2, kc = blockIdx.x & 3;
    const int row0 = mt * 128, k0 = kc * 1024;
    const int sr = tid >> 3;                 // 0..31
    const int cp = (tid & 7) ^ (sr & 7);
    const __hip_bfloat16* gX = Xa + (size_t)(row0 + sr) * KAUG + k0 + cp * 8;
    const __hip_bfloat16* gA = Ab + (size_t)sr * DIN + k0 + cp * 8;
    const int lr = lane & 15, lk = lane >> 4;
    f32x4 acc[2][8] = {};
    for (int kt = 0; kt < 16; ++kt) {
        #pragma unroll
        for (int i = 0; i < 4; ++i) {
            __builtin_amdgcn_global_load_lds((const uint32_t*)(gX + (size_t)(32 * i) * KAUG + kt * 64),
                                             (uint32_t*)(Xs + i * 4096 + tid * 16), 16, 0, 0);
            __builtin_amdgcn_global_load_lds((const uint32_t*)(gA + (size_t)(32 * i) * DIN + kt * 64),
                                             (uint32_t*)(As + i * 4096 + tid * 16), 16, 0, 0);
        }
        __syncthreads();
        #pragma unroll
        for (int kk = 0; kk < 2; ++kk) {
            short8 av[2], bv[8];
            #pragma unroll
            for (int m = 0; m < 2; ++m) {
                int row = wave * 32 + m * 16 + lr;
                int cc = (kk * 4 + lk) ^ (row & 7);
                av[m] = *(const short8*)(Xs + row * 128 + cc * 16);
            }
            #pragma unroll
            for (int n = 0; n < 8; ++n) {
                int row = n * 16 + lr;
                int cc = (kk * 4 + lk) ^ (row & 7);
                bv[n] = *(const short8*)(As + row * 128 + cc * 16);
            }
            #pragma unroll
            for (int m = 0; m < 2; ++m)
                #pragma unroll
                for (int n = 0; n < 8; ++n)
                    acc[m][n] = __builtin_amdgcn_mfma_f32_16x16x32_bf16(av[m], bv[n], acc[m][n], 0, 0, 0);
        }
        __syncthreads();
    }
    #pragma unroll
    for (int n = 0; n < 8; ++n) {
        int col = n * 16 + lr;
        #pragma unroll
        for (int m = 0; m < 2; ++m) {
            int r0 = wave * 32 + m * 16 + lk * 4;
            #pragma unroll
            for (int j = 0; j < 4; ++j)
                part[((size_t)kc << 20) + (size_t)(row0 + r0 + j) * 128 + col] = acc[m][n][j];
        }
    }
}

// ---------- reduce split-K partials, mask by adapter, scale, cvt -> xaug tail ----------
__global__ void xa_reduce(const float* __restrict__ part, const int* __restrict__ widx,
                          __hip_bfloat16* __restrict__ xaug) {
    int t = blockIdx.x * 256 + threadIdx.x;   // < 8192*128
    int s = t >> 7, c = t & 127;
    float sum = part[t] + part[(1 << 20) + t] + part[(2 << 20) + t] + part[(3 << 20) + t];
    int l = widx[s];
    float v = ((c >> 4) == l) ? 2.0f * sum : 0.0f;
    xaug[(size_t)s * KAUG + 4096 + c] = __float2bfloat16(v);
}

// ---------- 256x256 8-phase GEMM, cross-phase read pipeline + PINNED scheduling ----------
// 8 waves (2M x 4N), per-wave 128x64, BK=64, LDS 128KB double-buffered.
// Phase p: {STAGE | [vmcnt(4)] | BAR | ds_reads(p+1) | sched_barrier(0) |
//   setprio(1) 16xMFMA(p) setprio(0) | BAR}.
// The sched_barrier(0) pins the reads ABOVE the MFMA cluster (R7 lacked this;
// the scheduler could sink reads below the MFMAs, re-serializing the pipes).
// MMQ operands were read one phase earlier -> compiler's counted lgkm wait
// passes immediately (>=8 outstanding newer reads). No drain-all in the loop.
// vmcnt(4) ledger (audited R6/R7, correctness-proven in R7): P4 drains buf1,
// P8 drains buf0; 4 loads in flight is the loop invariant.
__global__ __launch_bounds__(512, 2) void gemm8(const __hip_bfloat16* __restrict__ Xa,
                                                const __hip_bfloat16* __restrict__ Wa,
                                                const float* __restrict__ bias,
                                                float* __restrict__ out) {
    // layout: buf0.A [0,32K) buf0.B [32K,64K) buf1.A [64K,96K) buf1.B [96K,128K)
    __shared__ __attribute__((aligned(16))) char lds[131072];

    const int tid = threadIdx.x;
    const int lane = tid & 63, wave = tid >> 6;
    const int wm = wave >> 2, wn = wave & 3;
    const int lr = lane & 15, lk = lane >> 4;

    // bijective XCD swizzle (512 blocks, 512 % 8 == 0)
    int wg = blockIdx.x;
    int swz = (wg & 7) * 64 + (wg >> 3);
    int bm = swz >> 4, bn = swz & 15;
    const int rowA0 = bm * 256, colB0 = bn * 256;

    // staging: linear LDS dest, inverse-swizzled global source (rule #21).
    // LDS[r][c16] = G[r][c16 ^ (r&7)]
    const int sr = tid >> 3;
    const int cp = (tid & 7) ^ (sr & 7);
    const __hip_bfloat16* srcA = Xa + (size_t)(rowA0 + sr) * KAUG + cp * 8;
    const __hip_bfloat16* srcB = Wa + (size_t)(colB0 + sr) * KAUG + cp * 8;
    char* const stgd = lds + tid * 16;

    auto STAGE = [&](int buf, int mat, int half, int kt) {
        const __hip_bfloat16* s0 = (mat ? srcB : srcA) + (size_t)(half * 128) * KAUG + kt * 64;
        char* d = stgd + buf * 65536 + mat * 32768 + half * 16384;
        __builtin_amdgcn_global_load_lds((const uint32_t*)s0, (uint32_t*)d, 16, 0, 0);
        __builtin_amdgcn_global_load_lds((const uint32_t*)(s0 + (size_t)64 * KAUG),
                                         (uint32_t*)(d + 8192), 16, 0, 0);
    };

    // hoisted ds_read bases: row&7 == lane&7 for every fragment row, so the
    // swizzled chunk is independent of m/mh/n -> base + compile-time offset.
    const char* adrA[2][2];
    const char* adrB[2][2];
    #pragma unroll
    for (int kk = 0; kk < 2; ++kk) {
        int ccx = ((kk * 4 + lk) ^ (lane & 7)) * 16;
        adrA[0][kk] = lds + (wm * 128 + lr) * 128 + ccx;
        adrB[0][kk] = lds + 32768 + (wn * 64 + lr) * 128 + ccx;
        adrA[1][kk] = adrA[0][kk] + 65536;
        adrB[1][kk] = adrB[0][kk] + 65536;
    }

    f32x4 acc[8][4] = {};
    short8 aA[4], aB[4], b0[4], b1[4];   // ping-pong fragment sets

    auto LDA_K = [&](short8 (&af)[4], int buf, int mh, int kk) {
        const char* a0 = adrA[buf][kk] + mh * 8192;
        #pragma unroll
        for (int m = 0; m < 4; ++m)
            af[m] = *(const short8*)(a0 + m * 2048);
    };
    auto LDB_K = [&](short8 (&bf)[4], int buf, int kk) {
        const char* b0p = adrB[buf][kk];
        #pragma unroll
        for (int n = 0; n < 4; ++n)
            bf[n] = *(const short8*)(b0p + n * 2048);
    };

// PIN: everything above (the just-issued ds_reads) stays above; then 16
// uninterrupted MFMAs whose operands are one-phase-old registers.
#define MMQ(AF, BF, MB)                                                            \
    do {                                                                           \
        __builtin_amdgcn_sched_barrier(0);                                         \
        __builtin_amdgcn_s_setprio(1);                                             \
        _Pragma("unroll")                                                          \
        for (int m = 0; m < 4; ++m)                                                \
            _Pragma("unroll")                                                      \
            for (int n = 0; n < 4; ++n)                                            \
                acc[(MB) + m][n] = __builtin_amdgcn_mfma_f32_16x16x32_bf16(        \
                    AF[m], BF[n], acc[(MB) + m][n], 0, 0, 0);                      \
        __builtin_amdgcn_s_setprio(0);                                             \
    } while (0)

#define BAR() __builtin_amdgcn_s_barrier()
#define VM4() asm volatile("s_waitcnt vmcnt(4)" ::: "memory")

    // prologue: buf0 <- t0 (8 loads); buf1.B <- t1 (4 loads)
    STAGE(0, 0, 0, 0); STAGE(0, 0, 1, 0);
    STAGE(0, 1, 0, 0); STAGE(0, 1, 1, 0);
    STAGE(1, 1, 0, 1); STAGE(1, 1, 1, 1);
    VM4();   // buf0 landed; 4 (buf1.B) in flight == steady-state entry
    BAR();
    LDA_K(aA, 0, 0, 0); LDB_K(b0, 0, 0);   // READS(P1)

    #pragma unroll 1
    for (int i = 0; i < NT / 2; ++i) {
        int t1 = 2 * i + 1;
        int t2 = 2 * i + 2; if (t2 > NT - 1) t2 = NT - 1;   // clamp keeps vmcnt uniform
        int t3 = 2 * i + 3; if (t3 > NT - 1) t3 = NT - 1;
        // P1: MMQ buf0 (mh0,kk0); READS(P2); stage buf1.A.h0 <- t1
        STAGE(1, 0, 0, t1);
        BAR();
        LDA_K(aB, 0, 0, 1); LDB_K(b1, 0, 1);
        MMQ(aA, b0, 0);
        BAR();
        // P2: MMQ (mh0,kk1); READS(P3); stage buf1.A.h1 <- t1
        STAGE(1, 0, 1, t1);
        BAR();
        LDA_K(aA, 0, 1, 0);
        MMQ(aB, b1, 0);
        BAR();
        // P3: MMQ (mh1,kk0); READS(P4); stage buf0.B.h0 <- t2 (buf0.B reads consumed @P2)
        STAGE(0, 1, 0, t2);
        BAR();
        LDA_K(aB, 0, 1, 1);
        MMQ(aA, b0, 4);
        BAR();
        // P4: MMQ (mh1,kk1); stage buf0.B.h1 <- t2; vmcnt(4)+BAR -> buf1 (t1) landed;
        //     READS(P5) from buf1 (safe after the barrier)
        STAGE(0, 1, 1, t2);
        VM4();
        BAR();
        LDA_K(aA, 1, 0, 0); LDB_K(b0, 1, 0);
        MMQ(aB, b1, 4);
        BAR();
        // P5: MMQ buf1 (mh0,kk0); READS(P6); stage buf0.A h0+h1 <- t2 (buf0.A consumed @P4)
        STAGE(0, 0, 0, t2); STAGE(0, 0, 1, t2);
        BAR();
        LDA_K(aB, 1, 0, 1); LDB_K(b1, 1, 1);
        MMQ(aA, b0, 0);
        BAR();
        // P6: MMQ (mh0,kk1); READS(P7); no stage
        BAR();
        LDA_K(aA, 1, 1, 0);
        MMQ(aB, b1, 0);
        BAR();
        // P7: MMQ (mh1,kk0); READS(P8); stage buf1.B.h0 <- t3 (buf1.B reads consumed @P6)
        STAGE(1, 1, 0, t3);
        BAR();
        LDA_K(aB, 1, 1, 1);
        MMQ(aA, b0, 4);
        BAR();
        // P8: MMQ (mh1,kk1); stage buf1.B.h1 <- t3; vmcnt(4)+BAR -> buf0 (t2) landed;
        //     READS(P1-next) from buf0
        STAGE(1, 1, 1, t3);
        VM4();
        BAR();
        LDA_K(aA, 0, 0, 0); LDB_K(b0, 0, 0);
        MMQ(aB, b1, 4);
        BAR();
    }

    // epilogue: C/D map col=lane&15, row=(lane>>4)*4+j  [m89]
    #pragma unroll
    for (int n = 0; n < 4; ++n) {
        int col = colB0 + wn * 64 + n * 16 + lr;
        float bv = bias[col];
        #pragma unroll
        for (int m = 0; m < 8; ++m) {
            int row0 = rowA0 + wm * 128 + m * 16 + lk * 4;
            #pragma unroll
            for (int j = 0; j < 4; ++j) {
                out[(size_t)(row0 + j) * DOUT + col] = acc[m][n][j] + bv;
            }
        }
    }
#undef MMQ
#undef BAR
#undef VM4
}

extern "C" void kernel_launch(void* const* d_in, const int* in_sizes, int n_in,
                              void* d_out, int out_size, void* d_ws, size_t ws_size,
                              hipStream_t stream) {
    const float* x      = (const float*)d_in[0];
    const float* weight = (const float*)d_in[1];
    const float* bias   = (const float*)d_in[2];
    const float* A_buf  = (const float*)d_in[3];
    const float* B_buf  = (const float*)d_in[4];
    const int*   widx   = (const int*)d_in[5];
    float* out = (float*)d_out;

    __hip_bfloat16* xaug = (__hip_bfloat16*)d_ws;                                    // [8192][4224]
    __hip_bfloat16* waug = (__hip_bfloat16*)((char*)d_ws + (size_t)SDIM * KAUG * 2); // [4096][4224]
    // d_out doubles as scratch before gemm8 overwrites it:
    __hip_bfloat16* abf  = (__hip_bfloat16*)d_out;                    // [128][4096] bf16 = 1MB
    float*          part = (float*)((char*)d_out + (1 << 20));        // [4][8192][128] f32 = 16MB

    // fused prep: x->bf16, W->bf16, B-tail, A->bf16
    prep_all<<<26880, 256, 0, stream>>>(x, weight, B_buf, A_buf, xaug, waug, abf);
    // XA_all partials (split-K x4)
    xa_gemm<<<64 * 4, 256, 0, stream>>>(xaug, abf, part);
    // reduce + adapter mask + scale -> xaug tail
    xa_reduce<<<(SDIM * 128) / 256, 256, 0, stream>>>(part, widx, xaug);
    // 8-phase 256^2 GEMM + bias
    gemm8<<<(SDIM / 256) * (DOUT / 256), 512, 0, stream>>>(xaug, waug, bias, out);
}

// Round 11
// 303.717 us; speedup vs baseline: 1.0641x; 1.0302x over previous
//
#include <hip/hip_runtime.h>
#include <hip/hip_bf16.h>
#include <cstdint>

#define SDIM 8192
#define DIN  4096
#define DOUT 4096
#define KAUG 4224   // 4096 + 8*16 LoRA extension
#define NADP 8
#define RLORA 16
#define NT 66       // K-tiles of 64

typedef __attribute__((ext_vector_type(8))) short short8;
typedef __attribute__((ext_vector_type(4))) float f32x4;

// ---------- fused prep: x->bf16, W->bf16, B-tail, A->bf16 in ONE launch ----------
__global__ __launch_bounds__(256) void prep_all(const float* __restrict__ x,
                         const float* __restrict__ W,
                         const float* __restrict__ B0,
                         const float* __restrict__ A,
                         __hip_bfloat16* __restrict__ xaug,
                         __hip_bfloat16* __restrict__ waug,
                         __hip_bfloat16* __restrict__ abf) {
    int b = blockIdx.x;
    if (b < 24576) {   // x or W conversion
        const float* src = (b < 16384) ? x : W;
        __hip_bfloat16* dst = (b < 16384) ? xaug : waug;
        long base = (b < 16384) ? (long)b * 2048 : (long)(b - 16384) * 2048;
        long e = base + (long)threadIdx.x * 8;
        int s = (int)(e >> 12);
        int k = (int)(e & 4095);
        const float4* p = (const float4*)(src + e);
        float4 v0 = p[0], v1 = p[1];
        union { __hip_bfloat16 h[8]; short8 v; } u;
        u.h[0] = __float2bfloat16(v0.x); u.h[1] = __float2bfloat16(v0.y);
        u.h[2] = __float2bfloat16(v0.z); u.h[3] = __float2bfloat16(v0.w);
        u.h[4] = __float2bfloat16(v1.x); u.h[5] = __float2bfloat16(v1.y);
        u.h[6] = __float2bfloat16(v1.z); u.h[7] = __float2bfloat16(v1.w);
        *(short8*)(dst + (size_t)s * KAUG + k) = u.v;
    } else if (b < 26624) {   // B tail: waug[n][4096 + l*16 + r] = B0[l][n][r]
        int t = (b - 24576) * 256 + threadIdx.x;
        int n = t >> 7, c = t & 127;
        int l = c >> 4, r = c & 15;
        waug[(size_t)n * KAUG + 4096 + c] =
            __float2bfloat16(B0[((size_t)l * DOUT + n) * RLORA + r]);
    } else {                  // A cvt: 128*4096 elems, 8/thread
        long e = ((long)(b - 26624) * 256 + threadIdx.x) * 8;
        const float4* p = (const float4*)(A + e);
        float4 v0 = p[0], v1 = p[1];
        union { __hip_bfloat16 h[8]; short8 v; } u;
        u.h[0] = __float2bfloat16(v0.x); u.h[1] = __float2bfloat16(v0.y);
        u.h[2] = __float2bfloat16(v0.z); u.h[3] = __float2bfloat16(v0.w);
        u.h[4] = __float2bfloat16(v1.x); u.h[5] = __float2bfloat16(v1.y);
        u.h[6] = __float2bfloat16(v1.z); u.h[7] = __float2bfloat16(v1.w);
        *(short8*)(abf + e) = u.v;
    }
}

// ---------- XA_all split-K mini-GEMM: part[kc][8192][128] = Xa[:, kc*1024:+1024] @ Ab^T ----------
__global__ __launch_bounds__(256) void xa_gemm(const __hip_bfloat16* __restrict__ Xa,
                                               const __hip_bfloat16* __restrict__ Ab,
                                               float* __restrict__ part) {
    __shared__ __attribute__((aligned(16))) char sm[32768];
    char* Xs = sm;              // [128][64] bf16
    char* As = sm + 16384;      // [128][64] bf16
    const int tid = threadIdx.x, lane = tid & 63, wave = tid >> 6;
    const int mt = blockIdx.x >> 2, kc = blockIdx.x & 3;
    const int row0 = mt * 128, k0 = kc * 1024;
    const int sr = tid >> 3;                 // 0..31
    const int cp = (tid & 7) ^ (sr & 7);
    const __hip_bfloat16* gX = Xa + (size_t)(row0 + sr) * KAUG + k0 + cp * 8;
    const __hip_bfloat16* gA = Ab + (size_t)sr * DIN + k0 + cp * 8;
    const int lr = lane & 15, lk = lane >> 4;
    f32x4 acc[2][8] = {};
    for (int kt = 0; kt < 16; ++kt) {
        #pragma unroll
        for (int i = 0; i < 4; ++i) {
            __builtin_amdgcn_global_load_lds((const uint32_t*)(gX + (size_t)(32 * i) * KAUG + kt * 64),
                                             (uint32_t*)(Xs + i * 4096 + tid * 16), 16, 0, 0);
            __builtin_amdgcn_global_load_lds((const uint32_t*)(gA + (size_t)(32 * i) * DIN + kt * 64),
                                             (uint32_t*)(As + i * 4096 + tid * 16), 16, 0, 0);
        }
        __syncthreads();
        #pragma unroll
        for (int kk = 0; kk < 2; ++kk) {
            short8 av[2], bv[8];
            #pragma unroll
            for (int m = 0; m < 2; ++m) {
                int row = wave * 32 + m * 16 + lr;
                int cc = (kk * 4 + lk) ^ (row & 7);
                av[m] = *(const short8*)(Xs + row * 128 + cc * 16);
            }
            #pragma unroll
            for (int n = 0; n < 8; ++n) {
                int row = n * 16 + lr;
                int cc = (kk * 4 + lk) ^ (row & 7);
                bv[n] = *(const short8*)(As + row * 128 + cc * 16);
            }
            #pragma unroll
            for (int m = 0; m < 2; ++m)
                #pragma unroll
                for (int n = 0; n < 8; ++n)
                    acc[m][n] = __builtin_amdgcn_mfma_f32_16x16x32_bf16(av[m], bv[n], acc[m][n], 0, 0, 0);
        }
        __syncthreads();
    }
    #pragma unroll
    for (int n = 0; n < 8; ++n) {
        int col = n * 16 + lr;
        #pragma unroll
        for (int m = 0; m < 2; ++m) {
            int r0 = wave * 32 + m * 16 + lk * 4;
            #pragma unroll
            for (int j = 0; j < 4; ++j)
                part[((size_t)kc << 20) + (size_t)(row0 + r0 + j) * 128 + col] = acc[m][n][j];
        }
    }
}

// ---------- reduce split-K partials, mask by adapter, scale, cvt -> xaug tail ----------
__global__ void xa_reduce(const float* __restrict__ part, const int* __restrict__ widx,
                          __hip_bfloat16* __restrict__ xaug) {
    int t = blockIdx.x * 256 + threadIdx.x;   // < 8192*128
    int s = t >> 7, c = t & 127;
    float sum = part[t] + part[(1 << 20) + t] + part[(2 << 20) + t] + part[(3 << 20) + t];
    int l = widx[s];
    float v = ((c >> 4) == l) ? 2.0f * sum : 0.0f;
    xaug[(size_t)s * KAUG + 4096 + c] = __float2bfloat16(v);
}

// ---------- 256x256 8-phase GEMM, SINGLE barrier per phase (wave-drift overlap) ----------
// 8 waves (2M x 4N), per-wave 128x64, BK=64, LDS 128KB double-buffered.
// Phase p: {STAGE(1 call) | [vmcnt(2) @P4,P8] | ds_reads(p) | BAR | lgkmcnt(0) +
//   sched_barrier(0) | setprio(1) 16xMFMA setprio(0)}  -- NO trailing barrier.
// Sync proof:
//  WAR: STAGE(R)@p is safe iff last LDS-read of R <= p-2: all waves passed
//   BAR(p-1) => each executed LGK0@(p-2) => reads@(p-2) retired. Staging map
//   (1B.h1@P1, 1A.h0@P2, 1A.h1@P3, 0B.h0@P4, 0B.h1@P5, 0A.h0@P6, 0A.h1@P7,
//   1B.h0@P8) satisfies this: last reads are buf0.A@P4, buf0.B@P2, buf1.A@P8,
//   buf1.B@P6 -- every stage >= lastread+2.
//  RAW: reads@P1 (buf0) after BAR(P8): all waves passed VM(2)@P8 which drains
//   buf0's 8 loads (P4..P7 stages). reads@P5 (buf1) after BAR(P4): VM(2)@P4
//   drains buf1's 8 (P8prev,P1,P2,P3). Outstanding at VM: 10 -> drain oldest 8.
// Waves drift within a phase: leader's ds_reads/stage overlap laggards' MFMAs.
__global__ __launch_bounds__(512, 2) void gemm8(const __hip_bfloat16* __restrict__ Xa,
                                                const __hip_bfloat16* __restrict__ Wa,
                                                const float* __restrict__ bias,
                                                float* __restrict__ out) {
    // layout: buf0.A [0,32K) buf0.B [32K,64K) buf1.A [64K,96K) buf1.B [96K,128K)
    __shared__ __attribute__((aligned(16))) char lds[131072];

    const int tid = threadIdx.x;
    const int lane = tid & 63, wave = tid >> 6;
    const int wm = wave >> 2, wn = wave & 3;
    const int lr = lane & 15, lk = lane >> 4;

    // bijective XCD swizzle (512 blocks, 512 % 8 == 0)
    int wg = blockIdx.x;
    int swz = (wg & 7) * 64 + (wg >> 3);
    int bm = swz >> 4, bn = swz & 15;
    const int rowA0 = bm * 256, colB0 = bn * 256;

    // staging: linear LDS dest, inverse-swizzled global source (rule #21).
    // LDS[r][c16] = G[r][c16 ^ (r&7)]
    const int sr = tid >> 3;
    const int cp = (tid & 7) ^ (sr & 7);
    const __hip_bfloat16* srcA = Xa + (size_t)(rowA0 + sr) * KAUG + cp * 8;
    const __hip_bfloat16* srcB = Wa + (size_t)(colB0 + sr) * KAUG + cp * 8;
    char* const stgd = lds + tid * 16;

    auto STAGE = [&](int buf, int mat, int half, int kt) {
        const __hip_bfloat16* s0 = (mat ? srcB : srcA) + (size_t)(half * 128) * KAUG + kt * 64;
        char* d = stgd + buf * 65536 + mat * 32768 + half * 16384;
        __builtin_amdgcn_global_load_lds((const uint32_t*)s0, (uint32_t*)d, 16, 0, 0);
        __builtin_amdgcn_global_load_lds((const uint32_t*)(s0 + (size_t)64 * KAUG),
                                         (uint32_t*)(d + 8192), 16, 0, 0);
    };

    // hoisted ds_read bases: row&7 == lane&7 for every fragment row.
    const char* adrA[2][2];
    const char* adrB[2][2];
    #pragma unroll
    for (int kk = 0; kk < 2; ++kk) {
        int ccx = ((kk * 4 + lk) ^ (lane & 7)) * 16;
        adrA[0][kk] = lds + (wm * 128 + lr) * 128 + ccx;
        adrB[0][kk] = lds + 32768 + (wn * 64 + lr) * 128 + ccx;
        adrA[1][kk] = adrA[0][kk] + 65536;
        adrB[1][kk] = adrB[0][kk] + 65536;
    }

    f32x4 acc[8][4] = {};
    short8 a[4], b0[4], b1[4];

    auto LDA_K = [&](short8 (&af)[4], int buf, int mh, int kk) {
        const char* a0 = adrA[buf][kk] + mh * 8192;
        #pragma unroll
        for (int m = 0; m < 4; ++m)
            af[m] = *(const short8*)(a0 + m * 2048);
    };
    auto LDB_K = [&](short8 (&bf)[4], int buf, int kk) {
        const char* b0p = adrB[buf][kk];
        #pragma unroll
        for (int n = 0; n < 4; ++n)
            bf[n] = *(const short8*)(b0p + n * 2048);
    };

// BAR, then drain-all + fence (rule #18), then 16 uninterrupted MFMAs.
#define MMQ(AF, BF, MB)                                                            \
    do {                                                                           \
        __builtin_amdgcn_s_barrier();                                              \
        asm volatile("s_waitcnt lgkmcnt(0)" ::: "memory");                         \
        __builtin_amdgcn_sched_barrier(0);                                         \
        __builtin_amdgcn_s_setprio(1);                                             \
        _Pragma("unroll")                                                          \
        for (int m = 0; m < 4; ++m)                                                \
            _Pragma("unroll")                                                      \
            for (int n = 0; n < 4; ++n)                                            \
                acc[(MB) + m][n] = __builtin_amdgcn_mfma_f32_16x16x32_bf16(        \
                    AF[m], BF[n], acc[(MB) + m][n], 0, 0, 0);                      \
        __builtin_amdgcn_s_setprio(0);                                             \
    } while (0)

#define VM2() asm volatile("s_waitcnt vmcnt(2)" ::: "memory")

    // prologue: buf0 <- t0 (8 loads); buf1.B.h0 <- t1 (2 loads); drain buf0.
    STAGE(0, 0, 0, 0); STAGE(0, 0, 1, 0);
    STAGE(0, 1, 0, 0); STAGE(0, 1, 1, 0);
    STAGE(1, 1, 0, 1);
    VM2();   // buf0's 8 landed; 2 (1B.h0) in flight == steady-state entry to P1
    __builtin_amdgcn_s_barrier();

    #pragma unroll 1
    for (int i = 0; i < NT / 2; ++i) {
        int t1 = 2 * i + 1;
        int t2 = 2 * i + 2; if (t2 > NT - 1) t2 = NT - 1;   // clamp keeps vmcnt uniform
        int t3 = 2 * i + 3; if (t3 > NT - 1) t3 = NT - 1;
        // P1: stage 1B.h1<-t1; reads buf0 (A mh0 kk0 + B kk0); BAR; MMQ
        STAGE(1, 1, 1, t1);
        LDA_K(a, 0, 0, 0); LDB_K(b0, 0, 0);
        MMQ(a, b0, 0);
        // P2: stage 1A.h0<-t1; reads buf0 (A mh0 kk1 + B kk1)
        STAGE(1, 0, 0, t1);
        LDA_K(a, 0, 0, 1); LDB_K(b1, 0, 1);
        MMQ(a, b1, 0);
        // P3: stage 1A.h1<-t1; reads buf0 (A mh1 kk0); b0 reused from regs
        STAGE(1, 0, 1, t1);
        LDA_K(a, 0, 1, 0);
        MMQ(a, b0, 4);
        // P4: stage 0B.h0<-t2; vmcnt(2) drains buf1 (P8prev+P1+P2+P3 = 8 oldest of 10)
        STAGE(0, 1, 0, t2);
        VM2();
        LDA_K(a, 0, 1, 1);
        MMQ(a, b1, 4);
        // P5: stage 0B.h1<-t2; reads buf1 (A mh0 kk0 + B kk0)
        STAGE(0, 1, 1, t2);
        LDA_K(a, 1, 0, 0); LDB_K(b0, 1, 0);
        MMQ(a, b0, 0);
        // P6: stage 0A.h0<-t2; reads buf1 (A mh0 kk1 + B kk1)
        STAGE(0, 0, 0, t2);
        LDA_K(a, 1, 0, 1); LDB_K(b1, 1, 1);
        MMQ(a, b1, 0);
        // P7: stage 0A.h1<-t2; reads buf1 (A mh1 kk0)
        STAGE(0, 0, 1, t2);
        LDA_K(a, 1, 1, 0);
        MMQ(a, b0, 4);
        // P8: stage 1B.h0<-t3; vmcnt(2) drains buf0 (P4..P7 = 8 oldest of 10)
        STAGE(1, 1, 0, t3);
        VM2();
        LDA_K(a, 1, 1, 1);
        MMQ(a, b1, 4);
    }

    // epilogue: C/D map col=lane&15, row=(lane>>4)*4+j  [m89]
    #pragma unroll
    for (int n = 0; n < 4; ++n) {
        int col = colB0 + wn * 64 + n * 16 + lr;
        float bv = bias[col];
        #pragma unroll
        for (int m = 0; m < 8; ++m) {
            int row0 = rowA0 + wm * 128 + m * 16 + lk * 4;
            #pragma unroll
            for (int j = 0; j < 4; ++j) {
                out[(size_t)(row0 + j) * DOUT + col] = acc[m][n][j] + bv;
            }
        }
    }
#undef MMQ
#undef VM2
}

extern "C" void kernel_launch(void* const* d_in, const int* in_sizes, int n_in,
                              void* d_out, int out_size, void* d_ws, size_t ws_size,
                              hipStream_t stream) {
    const float* x      = (const float*)d_in[0];
    const float* weight = (const float*)d_in[1];
    const float* bias   = (const float*)d_in[2];
    const float* A_buf  = (const float*)d_in[3];
    const float* B_buf  = (const float*)d_in[4];
    const int*   widx   = (const int*)d_in[5];
    float* out = (float*)d_out;

    __hip_bfloat16* xaug = (__hip_bfloat16*)d_ws;                                    // [8192][4224]
    __hip_bfloat16* waug = (__hip_bfloat16*)((char*)d_ws + (size_t)SDIM * KAUG * 2); // [4096][4224]
    // d_out doubles as scratch before gemm8 overwrites it:
    __hip_bfloat16* abf  = (__hip_bfloat16*)d_out;                    // [128][4096] bf16 = 1MB
    float*          part = (float*)((char*)d_out + (1 << 20));        // [4][8192][128] f32 = 16MB

    // fused prep: x->bf16, W->bf16, B-tail, A->bf16
    prep_all<<<26880, 256, 0, stream>>>(x, weight, B_buf, A_buf, xaug, waug, abf);
    // XA_all partials (split-K x4)
    xa_gemm<<<64 * 4, 256, 0, stream>>>(xaug, abf, part);
    // reduce + adapter mask + scale -> xaug tail
    xa_reduce<<<(SDIM * 128) / 256, 256, 0, stream>>>(part, widx, xaug);
    // 8-phase 256^2 GEMM + bias
    gemm8<<<(SDIM / 256) * (DOUT / 256), 512, 0, stream>>>(xaug, waug, bias, out);
}